// Round 1
// baseline (863.457 us; speedup 1.0000x reference)
//
#include <hip/hip_runtime.h>
#include <math.h>

#define NN 50000
#define NE 800000
#define NG 64
#define D 128
#define IMG 4096

// ---------------- graph preprocessing ----------------

__global__ void edge_pass1(const int* __restrict__ col, const float* __restrict__ ew,
                           float* __restrict__ deg, int* __restrict__ cnt) {
  int e = blockIdx.x * 256 + threadIdx.x;
  if (e < NE) {
    int c = col[e];
    atomicAdd(&deg[c], ew[e]);
    atomicAdd(&cnt[c], 1);
  }
}

__global__ void dis_kernel(const float* __restrict__ deg, float* __restrict__ dis) {
  int i = blockIdx.x * 256 + threadIdx.x;
  if (i < NN) dis[i] = 1.0f / sqrtf(deg[i] + 1.0f);
}

// single-block exclusive scan of cnt[NN] -> off[NN+1]
__global__ void scan_kernel(const int* __restrict__ cnt, int* __restrict__ off) {
  __shared__ int sd[1024];
  __shared__ int sbase;
  int t = threadIdx.x;
  if (t == 0) sbase = 0;
  __syncthreads();
  for (int chunk = 0; chunk < NN; chunk += 1024) {
    int i = chunk + t;
    int v = (i < NN) ? cnt[i] : 0;
    sd[t] = v;
    __syncthreads();
    for (int s = 1; s < 1024; s <<= 1) {
      int add = (t >= s) ? sd[t - s] : 0;
      __syncthreads();
      sd[t] += add;
      __syncthreads();
    }
    int base = sbase;
    if (i < NN) off[i + 1] = base + sd[t];
    __syncthreads();
    if (t == 1023) sbase = base + sd[1023];
    __syncthreads();
  }
  if (t == 0) off[0] = 0;
}

__global__ void fill_kernel(const int* __restrict__ row, const int* __restrict__ col,
                            const float* __restrict__ ew, const float* __restrict__ dis,
                            const int* __restrict__ off, int* __restrict__ wcur,
                            int* __restrict__ src_s, float* __restrict__ norm_s) {
  int e = blockIdx.x * 256 + threadIdx.x;
  if (e < NE) {
    int c = col[e];
    int r = row[e];
    int p = atomicAdd(&wcur[c], 1);
    int idx = off[c] + p;
    src_s[idx] = r;
    norm_s[idx] = dis[r] * ew[e] * dis[c];
  }
}

__global__ void gather_emb(const int* __restrict__ types, const float* __restrict__ emb,
                           float* __restrict__ x) {
  int tid = blockIdx.x * 256 + threadIdx.x;  // NN*32 threads, float4 each
  int i = tid >> 5;
  int j = tid & 31;
  if (i < NN) ((float4*)x)[i * 32 + j] = ((const float4*)emb)[types[i] * 32 + j];
}

// ---------------- node GEMM: out[i][n] = sum_k x[i][k] * W[n][k], K=D=128 ----------------

__global__ __launch_bounds__(256) void node_gemm(const float* __restrict__ x,
                                                 const float* __restrict__ W,
                                                 float* __restrict__ out) {
  __shared__ float xs[16][68];   // [k][m], pad to 68 (b128-aligned rows: 68*4=272=17*16)
  __shared__ float ws[16][132];  // [k][n], 132*4=528=33*16
  int t = threadIdx.x;
  int m0 = blockIdx.x * 64;
  int tm = t >> 4;  // 0..15 -> m = m0 + tm*4 + mi
  int tn = t & 15;  // 0..15 -> n = tn*8 + nj
  float acc[4][8] = {};
  for (int kt = 0; kt < D; kt += 16) {
    {  // stage x tile [64 m x 16 k] transposed
      int mm = m0 + (t >> 2);
      int kc = (t & 3) * 4;
      float4 v = make_float4(0.f, 0.f, 0.f, 0.f);
      if (mm < NN) v = *(const float4*)(x + (size_t)mm * D + kt + kc);
      int ml = t >> 2;
      xs[kc + 0][ml] = v.x; xs[kc + 1][ml] = v.y; xs[kc + 2][ml] = v.z; xs[kc + 3][ml] = v.w;
    }
    {  // stage W tile [128 n x 16 k] transposed
      int kc = (t & 3) * 4;
      #pragma unroll
      for (int r = 0; r < 2; r++) {
        int nn = (t >> 2) + r * 64;
        float4 v = *(const float4*)(W + (size_t)nn * D + kt + kc);
        ws[kc + 0][nn] = v.x; ws[kc + 1][nn] = v.y; ws[kc + 2][nn] = v.z; ws[kc + 3][nn] = v.w;
      }
    }
    __syncthreads();
    #pragma unroll
    for (int k = 0; k < 16; k++) {
      float4 xv = *(const float4*)&xs[k][tm * 4];
      float4 wa = *(const float4*)&ws[k][tn * 8];
      float4 wb = *(const float4*)&ws[k][tn * 8 + 4];
      float xm[4] = {xv.x, xv.y, xv.z, xv.w};
      float wn[8] = {wa.x, wa.y, wa.z, wa.w, wb.x, wb.y, wb.z, wb.w};
      #pragma unroll
      for (int mi = 0; mi < 4; mi++)
        #pragma unroll
        for (int nj = 0; nj < 8; nj++)
          acc[mi][nj] = fmaf(xm[mi], wn[nj], acc[mi][nj]);
    }
    __syncthreads();
  }
  #pragma unroll
  for (int mi = 0; mi < 4; mi++) {
    int mm = m0 + tm * 4 + mi;
    if (mm < NN) {
      float4 s0 = make_float4(acc[mi][0], acc[mi][1], acc[mi][2], acc[mi][3]);
      float4 s1 = make_float4(acc[mi][4], acc[mi][5], acc[mi][6], acc[mi][7]);
      *(float4*)(out + (size_t)mm * D + tn * 8) = s0;
      *(float4*)(out + (size_t)mm * D + tn * 8 + 4) = s1;
    }
  }
}

// ---------------- CSR aggregation: one wave per node ----------------

__global__ __launch_bounds__(256) void aggregate(const float* __restrict__ xw,
                                                 float* __restrict__ out,
                                                 const int* __restrict__ off,
                                                 const int* __restrict__ src_s,
                                                 const float* __restrict__ norm_s,
                                                 const float* __restrict__ dis,
                                                 const float* __restrict__ bias, int relu) {
  int wave = threadIdx.x >> 6;
  int lane = threadIdx.x & 63;
  int node = blockIdx.x * 4 + wave;
  if (node >= NN) return;
  const float2* xv = (const float2*)xw;
  float2 acc = make_float2(0.f, 0.f);
  int s = off[node], e = off[node + 1];
  for (int idx = s; idx < e; idx++) {
    int src = src_s[idx];
    float nm = norm_s[idx];
    float2 v = xv[(size_t)src * 64 + lane];
    acc.x = fmaf(nm, v.x, acc.x);
    acc.y = fmaf(nm, v.y, acc.y);
  }
  float dd = dis[node];
  dd = dd * dd;
  float2 v = xv[(size_t)node * 64 + lane];
  acc.x = fmaf(dd, v.x, acc.x);
  acc.y = fmaf(dd, v.y, acc.y);
  float2 b = ((const float2*)bias)[lane];
  acc.x += b.x;
  acc.y += b.y;
  if (relu) {
    acc.x = fmaxf(acc.x, 0.f);
    acc.y = fmaxf(acc.y, 0.f);
  }
  ((float2*)out)[(size_t)node * 64 + lane] = acc;
}

// ---------------- small-M GEMM: out[64][N] += A[64][K] * W[N][K]^T, k-split ----------------

__global__ __launch_bounds__(256) void biasinit(float* __restrict__ out,
                                                const float* __restrict__ bias, int N) {
  int idx = blockIdx.x * 256 + threadIdx.x;
  if (idx < 64 * N) out[idx] = bias[idx % N];
}

__global__ __launch_bounds__(256) void gemm64(const float* __restrict__ A,
                                              const float* __restrict__ W,
                                              float* __restrict__ out, int N, int K,
                                              int kChunk) {
  __shared__ float xs[16][68];  // [k][m]
  __shared__ float ws[16][68];  // [k][n]
  int t = threadIdx.x;
  int n0 = blockIdx.x * 64;
  int k0 = blockIdx.y * kChunk;
  int kEnd = min(K, k0 + kChunk);
  int tn = t & 15;  // n = n0 + tn*4 + ni
  int tm = t >> 4;  // m = tm*4 + mi
  float acc[4][4] = {};
  for (int kt = k0; kt < kEnd; kt += 16) {
    int kc = (t & 3) * 4;
    int rr = t >> 2;  // 0..63
    float4 va = *(const float4*)(A + (size_t)rr * K + kt + kc);
    xs[kc + 0][rr] = va.x; xs[kc + 1][rr] = va.y; xs[kc + 2][rr] = va.z; xs[kc + 3][rr] = va.w;
    float4 vw = *(const float4*)(W + (size_t)(n0 + rr) * K + kt + kc);
    ws[kc + 0][rr] = vw.x; ws[kc + 1][rr] = vw.y; ws[kc + 2][rr] = vw.z; ws[kc + 3][rr] = vw.w;
    __syncthreads();
    #pragma unroll
    for (int k = 0; k < 16; k++) {
      float4 xv = *(const float4*)&xs[k][tm * 4];
      float4 wv = *(const float4*)&ws[k][tn * 4];
      float xm[4] = {xv.x, xv.y, xv.z, xv.w};
      float wn[4] = {wv.x, wv.y, wv.z, wv.w};
      #pragma unroll
      for (int mi = 0; mi < 4; mi++)
        #pragma unroll
        for (int ni = 0; ni < 4; ni++)
          acc[mi][ni] = fmaf(xm[mi], wn[ni], acc[mi][ni]);
    }
    __syncthreads();
  }
  #pragma unroll
  for (int mi = 0; mi < 4; mi++)
    #pragma unroll
    for (int ni = 0; ni < 4; ni++)
      atomicAdd(&out[(size_t)(tm * 4 + mi) * N + n0 + tn * 4 + ni], acc[mi][ni]);
}

// ---------------- pooling + heads ----------------

__global__ void graph_bounds(const int* __restrict__ batch, int* __restrict__ goff) {
  int g = threadIdx.x;
  if (g <= NG) {
    int lo = 0, hi = NN;
    while (lo < hi) {
      int mid = (lo + hi) >> 1;
      if (batch[mid] < g) lo = mid + 1; else hi = mid;
    }
    goff[g] = lo;
  }
}

__global__ __launch_bounds__(128) void pool_kernel(const float* __restrict__ xg,
                                                   const int* __restrict__ goff,
                                                   float* __restrict__ pooled) {
  int g = blockIdx.x;
  int t = threadIdx.x;
  int s = goff[g], e = goff[g + 1];
  float acc = 0.f;
  int i = s;
  for (; i + 3 < e; i += 4) {
    acc += xg[(size_t)i * D + t] + xg[(size_t)(i + 1) * D + t] +
           xg[(size_t)(i + 2) * D + t] + xg[(size_t)(i + 3) * D + t];
  }
  for (; i < e; i++) acc += xg[(size_t)i * D + t];
  pooled[g * D + t] = acc / fmaxf((float)(e - s), 1.0f);
}

__global__ __launch_bounds__(256) void build_xcat(const float* __restrict__ xi,
                                                  const float* __restrict__ pooled,
                                                  float* __restrict__ xcat) {
  int idx = blockIdx.x * 256 + threadIdx.x;  // 64 * 1056 float4s
  if (idx < 64 * 1056) {
    int r = idx / 1056;
    int c = idx % 1056;
    float4 v = (c < 1024) ? ((const float4*)xi)[r * 1024 + c]
                          : ((const float4*)pooled)[r * 32 + (c - 1024)];
    ((float4*)xcat)[idx] = v;
  }
}

__global__ __launch_bounds__(128) void normalize_rows(const float* __restrict__ oi_raw,
                                                      const float* __restrict__ oc_raw,
                                                      float* __restrict__ out) {
  int r = blockIdx.x;  // 0..127; 0..63 -> oi, 64..127 -> oc
  int t = threadIdx.x;
  const float* src = (r < 64) ? (oi_raw + r * D) : (oc_raw + (r - 64) * D);
  float v = src[t];
  __shared__ float red[128];
  red[t] = v * v;
  __syncthreads();
  for (int s = 64; s > 0; s >>= 1) {
    if (t < s) red[t] += red[t + s];
    __syncthreads();
  }
  out[r * D + t] = v / sqrtf(red[0]);
}

// ---------------- launch ----------------

extern "C" void kernel_launch(void* const* d_in, const int* in_sizes, int n_in,
                              void* d_out, int out_size, void* d_ws, size_t ws_size,
                              hipStream_t stream) {
  const float* images = (const float*)d_in[0];
  const int* node_types = (const int*)d_in[1];
  const int* erow = (const int*)d_in[2];
  const int* ecol = erow + NE;
  const float* eattr = (const float*)d_in[3];
  const int* batch = (const int*)d_in[4];
  const float* emb = (const float*)d_in[5];
  const float* W_img = (const float*)d_in[6];
  const float* b_img = (const float*)d_in[7];
  const float* W1 = (const float*)d_in[8];
  const float* b1 = (const float*)d_in[9];
  const float* W2 = (const float*)d_in[10];
  const float* b2 = (const float*)d_in[11];
  const float* W3 = (const float*)d_in[12];
  const float* b3 = (const float*)d_in[13];
  const float* Wi = (const float*)d_in[14];
  const float* bi = (const float*)d_in[15];
  const float* Wc = (const float*)d_in[16];
  const float* bc = (const float*)d_in[17];
  float* out = (float*)d_out;

  // workspace carve (512B aligned)
  char* w = (char*)d_ws;
  auto alloc = [&](size_t bytes) -> void* {
    void* p = (void*)w;
    w += (bytes + 511) & ~(size_t)511;
    return p;
  };
  float* deg = (float*)alloc(NN * 4);
  int* cnt_i = (int*)alloc(NN * 4);
  int* wcur = (int*)alloc(NN * 4);
  size_t zero_bytes = (size_t)(w - (char*)d_ws);  // deg+cnt+wcur need zeroing
  int* csr_off = (int*)alloc((NN + 1) * 4);
  int* goff = (int*)alloc((NG + 1) * 4);
  int* src_s = (int*)alloc((size_t)NE * 4);
  float* norm_s = (float*)alloc((size_t)NE * 4);
  float* dis = (float*)alloc(NN * 4);
  float* bufA = (float*)alloc((size_t)NN * D * 4);
  float* bufB = (float*)alloc((size_t)NN * D * 4);
  float* xi = (float*)alloc((size_t)64 * IMG * 4);
  float* xcat = (float*)alloc((size_t)64 * (IMG + D) * 4);
  float* oi_raw = (float*)alloc(64 * D * 4);
  float* oc_raw = (float*)alloc(64 * D * 4);
  float* pooled = (float*)alloc(64 * D * 4);

  hipMemsetAsync(d_ws, 0, zero_bytes, stream);

  // graph preprocessing
  edge_pass1<<<NE / 256, 256, 0, stream>>>(ecol, eattr, deg, cnt_i);
  dis_kernel<<<(NN + 255) / 256, 256, 0, stream>>>(deg, dis);
  scan_kernel<<<1, 1024, 0, stream>>>(cnt_i, csr_off);
  fill_kernel<<<NE / 256, 256, 0, stream>>>(erow, ecol, eattr, dis, csr_off, wcur, src_s,
                                            norm_s);
  gather_emb<<<NN * 32 / 256, 256, 0, stream>>>(node_types, emb, bufA);

  // 3 GCN convs
  int nblk = (NN + 63) / 64;
  node_gemm<<<nblk, 256, 0, stream>>>(bufA, W1, bufB);
  aggregate<<<(NN + 3) / 4, 256, 0, stream>>>(bufB, bufA, csr_off, src_s, norm_s, dis, b1, 1);
  node_gemm<<<nblk, 256, 0, stream>>>(bufA, W2, bufB);
  aggregate<<<(NN + 3) / 4, 256, 0, stream>>>(bufB, bufA, csr_off, src_s, norm_s, dis, b2, 1);
  node_gemm<<<nblk, 256, 0, stream>>>(bufA, W3, bufB);
  aggregate<<<(NN + 3) / 4, 256, 0, stream>>>(bufB, bufA, csr_off, src_s, norm_s, dis, b3, 0);

  // pooling
  graph_bounds<<<1, 128, 0, stream>>>(batch, goff);
  pool_kernel<<<NG, 128, 0, stream>>>(bufA, goff, pooled);

  // image path: xi = images @ W_img.T + b_img
  biasinit<<<(64 * IMG + 255) / 256, 256, 0, stream>>>(xi, b_img, IMG);
  {
    dim3 g(IMG / 64, 8);
    gemm64<<<g, 256, 0, stream>>>(images, W_img, xi, IMG, IMG, 512);
  }
  // oi = normalize(xi @ Wi.T + bi)
  biasinit<<<(64 * D + 255) / 256, 256, 0, stream>>>(oi_raw, bi, D);
  {
    dim3 g(D / 64, 32);
    gemm64<<<g, 256, 0, stream>>>(xi, Wi, oi_raw, D, IMG, 128);
  }
  // oc = normalize(concat(xi, pooled) @ Wc.T + bc)
  build_xcat<<<(64 * 1056 + 255) / 256, 256, 0, stream>>>(xi, pooled, xcat);
  biasinit<<<(64 * D + 255) / 256, 256, 0, stream>>>(oc_raw, bc, D);
  {
    dim3 g(D / 64, 24);
    gemm64<<<g, 256, 0, stream>>>(xcat, Wc, oc_raw, D, IMG + D, 176);
  }
  normalize_rows<<<128, 128, 0, stream>>>(oi_raw, oc_raw, out);
}

// Round 2
// 746.606 us; speedup vs baseline: 1.1565x; 1.1565x over previous
//
#include <hip/hip_runtime.h>
#include <math.h>

#define NN 50000
#define NE 800000
#define NG 64
#define D 128
#define IMG 4096
#define SCAN_BLOCKS ((NN + 255) / 256)

// ---------------- graph preprocessing ----------------

__global__ void edge_pass1(const int* __restrict__ col, const float* __restrict__ ew,
                           float* __restrict__ deg, int* __restrict__ cnt) {
  int e = blockIdx.x * 256 + threadIdx.x;
  if (e < NE) {
    int c = col[e];
    atomicAdd(&deg[c], ew[e]);
    atomicAdd(&cnt[c], 1);
  }
}

__global__ void dis_kernel(const float* __restrict__ deg, float* __restrict__ dis) {
  int i = blockIdx.x * 256 + threadIdx.x;
  if (i < NN) dis[i] = 1.0f / sqrtf(deg[i] + 1.0f);
}

// ---- 3-level parallel exclusive scan of cnt[NN] -> off[NN+1] ----

__global__ __launch_bounds__(256) void scan_blocks(const int* __restrict__ cnt,
                                                   int* __restrict__ incl,
                                                   int* __restrict__ partial) {
  __shared__ int sd[256];
  int t = threadIdx.x;
  int i = blockIdx.x * 256 + t;
  int v = (i < NN) ? cnt[i] : 0;
  sd[t] = v;
  __syncthreads();
  #pragma unroll
  for (int s = 1; s < 256; s <<= 1) {
    int add = (t >= s) ? sd[t - s] : 0;
    __syncthreads();
    sd[t] += add;
    __syncthreads();
  }
  if (i < NN) incl[i] = sd[t];
  if (t == 255) partial[blockIdx.x] = sd[255];
}

__global__ __launch_bounds__(256) void scan_partials(int* __restrict__ partial, int nb) {
  __shared__ int sd[256];
  int t = threadIdx.x;
  int v = (t < nb) ? partial[t] : 0;
  sd[t] = v;
  __syncthreads();
  #pragma unroll
  for (int s = 1; s < 256; s <<= 1) {
    int add = (t >= s) ? sd[t - s] : 0;
    __syncthreads();
    sd[t] += add;
    __syncthreads();
  }
  if (t < nb) partial[t] = (t == 0) ? 0 : sd[t - 1];
}

__global__ __launch_bounds__(256) void scan_apply(const int* __restrict__ incl,
                                                  const int* __restrict__ partial,
                                                  int* __restrict__ off) {
  int i = blockIdx.x * 256 + threadIdx.x;
  if (i < NN) off[i + 1] = incl[i] + partial[blockIdx.x];
  if (i == 0) off[0] = 0;
}

__global__ void fill_kernel(const int* __restrict__ row, const int* __restrict__ col,
                            const float* __restrict__ ew, const float* __restrict__ dis,
                            const int* __restrict__ off, int* __restrict__ wcur,
                            int* __restrict__ src_s, float* __restrict__ norm_s) {
  int e = blockIdx.x * 256 + threadIdx.x;
  if (e < NE) {
    int c = col[e];
    int r = row[e];
    int p = atomicAdd(&wcur[c], 1);
    int idx = off[c] + p;
    src_s[idx] = r;
    norm_s[idx] = dis[r] * ew[e] * dis[c];
  }
}

__global__ void gather_emb(const int* __restrict__ types, const float* __restrict__ emb,
                           float* __restrict__ x) {
  int tid = blockIdx.x * 256 + threadIdx.x;  // NN*32 threads, float4 each
  int i = tid >> 5;
  int j = tid & 31;
  if (i < NN) ((float4*)x)[i * 32 + j] = ((const float4*)emb)[types[i] * 32 + j];
}

// ---------------- node GEMM: out[i][n] = sum_k x[i][k] * W[n][k], K=D=128 ----------------

__global__ __launch_bounds__(256) void node_gemm(const float* __restrict__ x,
                                                 const float* __restrict__ W,
                                                 float* __restrict__ out) {
  __shared__ float xs[16][68];   // [k][m]
  __shared__ float ws[16][132];  // [k][n]
  int t = threadIdx.x;
  int m0 = blockIdx.x * 64;
  int tm = t >> 4;  // 0..15 -> m = m0 + tm*4 + mi
  int tn = t & 15;  // 0..15 -> n = tn*8 + nj
  float acc[4][8] = {};
  for (int kt = 0; kt < D; kt += 16) {
    {  // stage x tile [64 m x 16 k] transposed
      int mm = m0 + (t >> 2);
      int kc = (t & 3) * 4;
      float4 v = make_float4(0.f, 0.f, 0.f, 0.f);
      if (mm < NN) v = *(const float4*)(x + (size_t)mm * D + kt + kc);
      int ml = t >> 2;
      xs[kc + 0][ml] = v.x; xs[kc + 1][ml] = v.y; xs[kc + 2][ml] = v.z; xs[kc + 3][ml] = v.w;
    }
    {  // stage W tile [128 n x 16 k] transposed
      int kc = (t & 3) * 4;
      #pragma unroll
      for (int r = 0; r < 2; r++) {
        int nn = (t >> 2) + r * 64;
        float4 v = *(const float4*)(W + (size_t)nn * D + kt + kc);
        ws[kc + 0][nn] = v.x; ws[kc + 1][nn] = v.y; ws[kc + 2][nn] = v.z; ws[kc + 3][nn] = v.w;
      }
    }
    __syncthreads();
    #pragma unroll
    for (int k = 0; k < 16; k++) {
      float4 xv = *(const float4*)&xs[k][tm * 4];
      float4 wa = *(const float4*)&ws[k][tn * 8];
      float4 wb = *(const float4*)&ws[k][tn * 8 + 4];
      float xm[4] = {xv.x, xv.y, xv.z, xv.w};
      float wn[8] = {wa.x, wa.y, wa.z, wa.w, wb.x, wb.y, wb.z, wb.w};
      #pragma unroll
      for (int mi = 0; mi < 4; mi++)
        #pragma unroll
        for (int nj = 0; nj < 8; nj++)
          acc[mi][nj] = fmaf(xm[mi], wn[nj], acc[mi][nj]);
    }
    __syncthreads();
  }
  #pragma unroll
  for (int mi = 0; mi < 4; mi++) {
    int mm = m0 + tm * 4 + mi;
    if (mm < NN) {
      float4 s0 = make_float4(acc[mi][0], acc[mi][1], acc[mi][2], acc[mi][3]);
      float4 s1 = make_float4(acc[mi][4], acc[mi][5], acc[mi][6], acc[mi][7]);
      *(float4*)(out + (size_t)mm * D + tn * 8) = s0;
      *(float4*)(out + (size_t)mm * D + tn * 8 + 4) = s1;
    }
  }
}

// ---------------- CSR aggregation: one wave per node ----------------

__global__ __launch_bounds__(256) void aggregate(const float* __restrict__ xw,
                                                 float* __restrict__ out,
                                                 const int* __restrict__ off,
                                                 const int* __restrict__ src_s,
                                                 const float* __restrict__ norm_s,
                                                 const float* __restrict__ dis,
                                                 const float* __restrict__ bias, int relu) {
  int wave = threadIdx.x >> 6;
  int lane = threadIdx.x & 63;
  int node = blockIdx.x * 4 + wave;
  if (node >= NN) return;
  const float2* xv = (const float2*)xw;
  float2 acc = make_float2(0.f, 0.f);
  int s = off[node], e = off[node + 1];
  for (int idx = s; idx < e; idx++) {
    int src = src_s[idx];
    float nm = norm_s[idx];
    float2 v = xv[(size_t)src * 64 + lane];
    acc.x = fmaf(nm, v.x, acc.x);
    acc.y = fmaf(nm, v.y, acc.y);
  }
  float dd = dis[node];
  dd = dd * dd;
  float2 v = xv[(size_t)node * 64 + lane];
  acc.x = fmaf(dd, v.x, acc.x);
  acc.y = fmaf(dd, v.y, acc.y);
  float2 b = ((const float2*)bias)[lane];
  acc.x += b.x;
  acc.y += b.y;
  if (relu) {
    acc.x = fmaxf(acc.x, 0.f);
    acc.y = fmaxf(acc.y, 0.f);
  }
  ((float2*)out)[(size_t)node * 64 + lane] = acc;
}

// ---------------- small-M GEMM: out[64][N] += A[64][K] * W[N][K]^T, k-split ----------------

__global__ __launch_bounds__(256) void biasinit(float* __restrict__ out,
                                                const float* __restrict__ bias, int N) {
  int idx = blockIdx.x * 256 + threadIdx.x;
  if (idx < 64 * N) out[idx] = bias[idx % N];
}

__global__ __launch_bounds__(256) void gemm64(const float* __restrict__ A,
                                              const float* __restrict__ W,
                                              float* __restrict__ out, int N, int K,
                                              int kChunk) {
  __shared__ float xs[16][68];  // [k][m]
  __shared__ float ws[16][68];  // [k][n]
  int t = threadIdx.x;
  int n0 = blockIdx.x * 64;
  int k0 = blockIdx.y * kChunk;
  int kEnd = min(K, k0 + kChunk);
  int tn = t & 15;  // n = n0 + tn*4 + ni
  int tm = t >> 4;  // m = tm*4 + mi
  float acc[4][4] = {};
  for (int kt = k0; kt < kEnd; kt += 16) {
    int kc = (t & 3) * 4;
    int rr = t >> 2;  // 0..63
    float4 va = *(const float4*)(A + (size_t)rr * K + kt + kc);
    xs[kc + 0][rr] = va.x; xs[kc + 1][rr] = va.y; xs[kc + 2][rr] = va.z; xs[kc + 3][rr] = va.w;
    float4 vw = *(const float4*)(W + (size_t)(n0 + rr) * K + kt + kc);
    ws[kc + 0][rr] = vw.x; ws[kc + 1][rr] = vw.y; ws[kc + 2][rr] = vw.z; ws[kc + 3][rr] = vw.w;
    __syncthreads();
    #pragma unroll
    for (int k = 0; k < 16; k++) {
      float4 xv = *(const float4*)&xs[k][tm * 4];
      float4 wv = *(const float4*)&ws[k][tn * 4];
      float xm[4] = {xv.x, xv.y, xv.z, xv.w};
      float wn[4] = {wv.x, wv.y, wv.z, wv.w};
      #pragma unroll
      for (int mi = 0; mi < 4; mi++)
        #pragma unroll
        for (int ni = 0; ni < 4; ni++)
          acc[mi][ni] = fmaf(xm[mi], wn[ni], acc[mi][ni]);
    }
    __syncthreads();
  }
  #pragma unroll
  for (int mi = 0; mi < 4; mi++)
    #pragma unroll
    for (int ni = 0; ni < 4; ni++)
      atomicAdd(&out[(size_t)(tm * 4 + mi) * N + n0 + tn * 4 + ni], acc[mi][ni]);
}

// ---------------- pooling + heads ----------------

__global__ void graph_bounds(const int* __restrict__ batch, int* __restrict__ goff) {
  int g = threadIdx.x;
  if (g <= NG) {
    int lo = 0, hi = NN;
    while (lo < hi) {
      int mid = (lo + hi) >> 1;
      if (batch[mid] < g) lo = mid + 1; else hi = mid;
    }
    goff[g] = lo;
  }
}

__global__ __launch_bounds__(128) void pool_partial(const float* __restrict__ xg,
                                                    const int* __restrict__ goff,
                                                    float* __restrict__ pooled) {
  int g = blockIdx.x;
  int chunk = blockIdx.y;  // 0..7
  int t = threadIdx.x;
  int s = goff[g], e = goff[g + 1];
  float acc = 0.f;
  for (int i = s + chunk; i < e; i += 8) acc += xg[(size_t)i * D + t];
  atomicAdd(&pooled[g * D + t], acc);
}

__global__ __launch_bounds__(128) void pool_finish(float* __restrict__ pooled,
                                                   const int* __restrict__ goff) {
  int g = blockIdx.x;
  int t = threadIdx.x;
  int c = goff[g + 1] - goff[g];
  pooled[g * D + t] /= fmaxf((float)c, 1.0f);
}

__global__ __launch_bounds__(256) void build_xcat(const float* __restrict__ xi,
                                                  const float* __restrict__ pooled,
                                                  float* __restrict__ xcat) {
  int idx = blockIdx.x * 256 + threadIdx.x;  // 64 * 1056 float4s
  if (idx < 64 * 1056) {
    int r = idx / 1056;
    int c = idx % 1056;
    float4 v = (c < 1024) ? ((const float4*)xi)[r * 1024 + c]
                          : ((const float4*)pooled)[r * 32 + (c - 1024)];
    ((float4*)xcat)[idx] = v;
  }
}

__global__ __launch_bounds__(128) void normalize_rows(const float* __restrict__ oi_raw,
                                                      const float* __restrict__ oc_raw,
                                                      float* __restrict__ out) {
  int r = blockIdx.x;  // 0..127; 0..63 -> oi, 64..127 -> oc
  int t = threadIdx.x;
  const float* src = (r < 64) ? (oi_raw + r * D) : (oc_raw + (r - 64) * D);
  float v = src[t];
  __shared__ float red[128];
  red[t] = v * v;
  __syncthreads();
  for (int s = 64; s > 0; s >>= 1) {
    if (t < s) red[t] += red[t + s];
    __syncthreads();
  }
  out[r * D + t] = v / sqrtf(red[0]);
}

// ---------------- launch ----------------

extern "C" void kernel_launch(void* const* d_in, const int* in_sizes, int n_in,
                              void* d_out, int out_size, void* d_ws, size_t ws_size,
                              hipStream_t stream) {
  const float* images = (const float*)d_in[0];
  const int* node_types = (const int*)d_in[1];
  const int* erow = (const int*)d_in[2];
  const int* ecol = erow + NE;
  const float* eattr = (const float*)d_in[3];
  const int* batch = (const int*)d_in[4];
  const float* emb = (const float*)d_in[5];
  const float* W_img = (const float*)d_in[6];
  const float* b_img = (const float*)d_in[7];
  const float* W1 = (const float*)d_in[8];
  const float* b1 = (const float*)d_in[9];
  const float* W2 = (const float*)d_in[10];
  const float* b2 = (const float*)d_in[11];
  const float* W3 = (const float*)d_in[12];
  const float* b3 = (const float*)d_in[13];
  const float* Wi = (const float*)d_in[14];
  const float* bi = (const float*)d_in[15];
  const float* Wc = (const float*)d_in[16];
  const float* bc = (const float*)d_in[17];
  float* out = (float*)d_out;

  // workspace carve (512B aligned)
  char* w = (char*)d_ws;
  auto alloc = [&](size_t bytes) -> void* {
    void* p = (void*)w;
    w += (bytes + 511) & ~(size_t)511;
    return p;
  };
  float* deg = (float*)alloc(NN * 4);
  int* cnt_i = (int*)alloc(NN * 4);
  int* wcur = (int*)alloc(NN * 4);
  float* pooled = (float*)alloc(64 * D * 4);
  size_t zero_bytes = (size_t)(w - (char*)d_ws);  // deg+cnt+wcur+pooled need zeroing
  int* csr_off = (int*)alloc((NN + 1) * 4);
  int* goff = (int*)alloc((NG + 1) * 4);
  int* scan_incl = (int*)alloc(NN * 4);
  int* scan_part = (int*)alloc(SCAN_BLOCKS * 4);
  int* src_s = (int*)alloc((size_t)NE * 4);
  float* norm_s = (float*)alloc((size_t)NE * 4);
  float* dis = (float*)alloc(NN * 4);
  float* bufA = (float*)alloc((size_t)NN * D * 4);
  float* bufB = (float*)alloc((size_t)NN * D * 4);
  float* xi = (float*)alloc((size_t)64 * IMG * 4);
  float* xcat = (float*)alloc((size_t)64 * (IMG + D) * 4);
  float* oi_raw = (float*)alloc(64 * D * 4);
  float* oc_raw = (float*)alloc(64 * D * 4);

  hipMemsetAsync(d_ws, 0, zero_bytes, stream);

  // graph preprocessing
  edge_pass1<<<NE / 256, 256, 0, stream>>>(ecol, eattr, deg, cnt_i);
  dis_kernel<<<(NN + 255) / 256, 256, 0, stream>>>(deg, dis);
  scan_blocks<<<SCAN_BLOCKS, 256, 0, stream>>>(cnt_i, scan_incl, scan_part);
  scan_partials<<<1, 256, 0, stream>>>(scan_part, SCAN_BLOCKS);
  scan_apply<<<SCAN_BLOCKS, 256, 0, stream>>>(scan_incl, scan_part, csr_off);
  fill_kernel<<<NE / 256, 256, 0, stream>>>(erow, ecol, eattr, dis, csr_off, wcur, src_s,
                                            norm_s);
  gather_emb<<<NN * 32 / 256, 256, 0, stream>>>(node_types, emb, bufA);

  // 3 GCN convs
  int nblk = (NN + 63) / 64;
  node_gemm<<<nblk, 256, 0, stream>>>(bufA, W1, bufB);
  aggregate<<<(NN + 3) / 4, 256, 0, stream>>>(bufB, bufA, csr_off, src_s, norm_s, dis, b1, 1);
  node_gemm<<<nblk, 256, 0, stream>>>(bufA, W2, bufB);
  aggregate<<<(NN + 3) / 4, 256, 0, stream>>>(bufB, bufA, csr_off, src_s, norm_s, dis, b2, 1);
  node_gemm<<<nblk, 256, 0, stream>>>(bufA, W3, bufB);
  aggregate<<<(NN + 3) / 4, 256, 0, stream>>>(bufB, bufA, csr_off, src_s, norm_s, dis, b3, 0);

  // pooling
  graph_bounds<<<1, 128, 0, stream>>>(batch, goff);
  {
    dim3 g(NG, 8);
    pool_partial<<<g, 128, 0, stream>>>(bufA, goff, pooled);
  }
  pool_finish<<<NG, 128, 0, stream>>>(pooled, goff);

  // image path: xi = images @ W_img.T + b_img
  biasinit<<<(64 * IMG + 255) / 256, 256, 0, stream>>>(xi, b_img, IMG);
  {
    dim3 g(IMG / 64, 8);
    gemm64<<<g, 256, 0, stream>>>(images, W_img, xi, IMG, IMG, 512);
  }
  // oi = normalize(xi @ Wi.T + bi)
  biasinit<<<(64 * D + 255) / 256, 256, 0, stream>>>(oi_raw, bi, D);
  {
    dim3 g(D / 64, 32);
    gemm64<<<g, 256, 0, stream>>>(xi, Wi, oi_raw, D, IMG, 128);
  }
  // oc = normalize(concat(xi, pooled) @ Wc.T + bc)
  build_xcat<<<(64 * 1056 + 255) / 256, 256, 0, stream>>>(xi, pooled, xcat);
  biasinit<<<(64 * D + 255) / 256, 256, 0, stream>>>(oc_raw, bc, D);
  {
    dim3 g(D / 64, 24);
    gemm64<<<g, 256, 0, stream>>>(xcat, Wc, oc_raw, D, IMG + D, 176);
  }
  normalize_rows<<<128, 128, 0, stream>>>(oi_raw, oc_raw, out);
}

// Round 3
// 641.694 us; speedup vs baseline: 1.3456x; 1.1635x over previous
//
#include <hip/hip_runtime.h>
#include <math.h>

#define NN 50000
#define NE 800000
#define NG 64
#define D 128
#define IMG 4096
#define SCAN_BLOCKS ((NN + 255) / 256)

typedef unsigned int uint;

// bf16 helpers (bit-level, RNE pack / shift unpack)
__device__ __forceinline__ uint bf16rne(float f) {
  uint h = __float_as_uint(f);
  return (h + 0x7fffu + ((h >> 16) & 1u)) >> 16;
}
__device__ __forceinline__ uint pack2bf(float a, float b) {
  return bf16rne(a) | (bf16rne(b) << 16);
}

// ---------------- graph preprocessing ----------------

__global__ void edge_pass1(const int* __restrict__ col, const float* __restrict__ ew,
                           float* __restrict__ deg, int* __restrict__ cnt) {
  int e = blockIdx.x * 256 + threadIdx.x;
  if (e < NE) {
    int c = col[e];
    atomicAdd(&deg[c], ew[e]);
    atomicAdd(&cnt[c], 1);
  }
}

__global__ void dis_kernel(const float* __restrict__ deg, float* __restrict__ dis) {
  int i = blockIdx.x * 256 + threadIdx.x;
  if (i < NN) dis[i] = 1.0f / sqrtf(deg[i] + 1.0f);
}

// ---- 3-level parallel exclusive scan of cnt[NN] -> off[NN+1] ----

__global__ __launch_bounds__(256) void scan_blocks(const int* __restrict__ cnt,
                                                   int* __restrict__ incl,
                                                   int* __restrict__ partial) {
  __shared__ int sd[256];
  int t = threadIdx.x;
  int i = blockIdx.x * 256 + t;
  int v = (i < NN) ? cnt[i] : 0;
  sd[t] = v;
  __syncthreads();
  #pragma unroll
  for (int s = 1; s < 256; s <<= 1) {
    int add = (t >= s) ? sd[t - s] : 0;
    __syncthreads();
    sd[t] += add;
    __syncthreads();
  }
  if (i < NN) incl[i] = sd[t];
  if (t == 255) partial[blockIdx.x] = sd[255];
}

__global__ __launch_bounds__(256) void scan_partials(int* __restrict__ partial, int nb) {
  __shared__ int sd[256];
  int t = threadIdx.x;
  int v = (t < nb) ? partial[t] : 0;
  sd[t] = v;
  __syncthreads();
  #pragma unroll
  for (int s = 1; s < 256; s <<= 1) {
    int add = (t >= s) ? sd[t - s] : 0;
    __syncthreads();
    sd[t] += add;
    __syncthreads();
  }
  if (t < nb) partial[t] = (t == 0) ? 0 : sd[t - 1];
}

__global__ __launch_bounds__(256) void scan_apply(const int* __restrict__ incl,
                                                  const int* __restrict__ partial,
                                                  int* __restrict__ off) {
  int i = blockIdx.x * 256 + threadIdx.x;
  if (i < NN) off[i + 1] = incl[i] + partial[blockIdx.x];
  if (i == 0) off[0] = 0;
}

__global__ void fill_kernel(const int* __restrict__ row, const int* __restrict__ col,
                            const float* __restrict__ ew, const float* __restrict__ dis,
                            const int* __restrict__ off, int* __restrict__ wcur,
                            int* __restrict__ src_s, float* __restrict__ norm_s) {
  int e = blockIdx.x * 256 + threadIdx.x;
  if (e < NE) {
    int c = col[e];
    int r = row[e];
    int p = atomicAdd(&wcur[c], 1);
    int idx = off[c] + p;
    src_s[idx] = r;
    norm_s[idx] = dis[r] * ew[e] * dis[c];
  }
}

__global__ void gather_emb(const int* __restrict__ types, const float* __restrict__ emb,
                           float* __restrict__ x) {
  int tid = blockIdx.x * 256 + threadIdx.x;  // NN*32 threads, float4 each
  int i = tid >> 5;
  int j = tid & 31;
  if (i < NN) ((float4*)x)[i * 32 + j] = ((const float4*)emb)[types[i] * 32 + j];
}

// ---------------- node GEMM: out[i][n] = sum_k x[i][k] * W[n][k], K=D=128 ----------------
// Output packed bf16 (RNE) for the aggregation gather.

__global__ __launch_bounds__(256) void node_gemm(const float* __restrict__ x,
                                                 const float* __restrict__ W,
                                                 uint* __restrict__ outbf) {
  __shared__ float xs[16][68];   // [k][m]
  __shared__ float ws[16][132];  // [k][n]
  int t = threadIdx.x;
  int m0 = blockIdx.x * 64;
  int tm = t >> 4;  // 0..15 -> m = m0 + tm*4 + mi
  int tn = t & 15;  // 0..15 -> n = tn*8 + nj
  float acc[4][8] = {};
  for (int kt = 0; kt < D; kt += 16) {
    {  // stage x tile [64 m x 16 k] transposed
      int mm = m0 + (t >> 2);
      int kc = (t & 3) * 4;
      float4 v = make_float4(0.f, 0.f, 0.f, 0.f);
      if (mm < NN) v = *(const float4*)(x + (size_t)mm * D + kt + kc);
      int ml = t >> 2;
      xs[kc + 0][ml] = v.x; xs[kc + 1][ml] = v.y; xs[kc + 2][ml] = v.z; xs[kc + 3][ml] = v.w;
    }
    {  // stage W tile [128 n x 16 k] transposed
      int kc = (t & 3) * 4;
      #pragma unroll
      for (int r = 0; r < 2; r++) {
        int nn = (t >> 2) + r * 64;
        float4 v = *(const float4*)(W + (size_t)nn * D + kt + kc);
        ws[kc + 0][nn] = v.x; ws[kc + 1][nn] = v.y; ws[kc + 2][nn] = v.z; ws[kc + 3][nn] = v.w;
      }
    }
    __syncthreads();
    #pragma unroll
    for (int k = 0; k < 16; k++) {
      float4 xv = *(const float4*)&xs[k][tm * 4];
      float4 wa = *(const float4*)&ws[k][tn * 8];
      float4 wb = *(const float4*)&ws[k][tn * 8 + 4];
      float xm[4] = {xv.x, xv.y, xv.z, xv.w};
      float wn[8] = {wa.x, wa.y, wa.z, wa.w, wb.x, wb.y, wb.z, wb.w};
      #pragma unroll
      for (int mi = 0; mi < 4; mi++)
        #pragma unroll
        for (int nj = 0; nj < 8; nj++)
          acc[mi][nj] = fmaf(xm[mi], wn[nj], acc[mi][nj]);
    }
    __syncthreads();
  }
  #pragma unroll
  for (int mi = 0; mi < 4; mi++) {
    int mm = m0 + tm * 4 + mi;
    if (mm < NN) {
      uint4 o;
      o.x = pack2bf(acc[mi][0], acc[mi][1]);
      o.y = pack2bf(acc[mi][2], acc[mi][3]);
      o.z = pack2bf(acc[mi][4], acc[mi][5]);
      o.w = pack2bf(acc[mi][6], acc[mi][7]);
      *(uint4*)(outbf + (size_t)mm * 64 + tn * 4) = o;  // 64 uints per row (128 bf16)
    }
  }
}

// ---------------- CSR aggregation: one wave per node, bf16 gather, 4x MLP ----------------

__global__ __launch_bounds__(256) void aggregate(const uint* __restrict__ xw,
                                                 float* __restrict__ out,
                                                 const int* __restrict__ off,
                                                 const int* __restrict__ src_s,
                                                 const float* __restrict__ norm_s,
                                                 const float* __restrict__ dis,
                                                 const float* __restrict__ bias, int relu) {
  int wave = threadIdx.x >> 6;
  int lane = threadIdx.x & 63;
  int node = blockIdx.x * 4 + wave;
  if (node >= NN) return;
  float accx = 0.f, accy = 0.f;
  int s = off[node], e = off[node + 1];
  int idx = s;
  int astart = (s + 3) & ~3;
  if (astart > e) astart = e;
  for (; idx < astart; idx++) {
    int src = src_s[idx];
    float nm = norm_s[idx];
    uint u = xw[(size_t)src * 64 + lane];
    accx = fmaf(nm, __uint_as_float(u << 16), accx);
    accy = fmaf(nm, __uint_as_float(u & 0xffff0000u), accy);
  }
  for (; idx + 4 <= e; idx += 4) {
    int4 sr = *(const int4*)(src_s + idx);
    float4 nm = *(const float4*)(norm_s + idx);
    uint u0 = xw[(size_t)sr.x * 64 + lane];
    uint u1 = xw[(size_t)sr.y * 64 + lane];
    uint u2 = xw[(size_t)sr.z * 64 + lane];
    uint u3 = xw[(size_t)sr.w * 64 + lane];
    accx = fmaf(nm.x, __uint_as_float(u0 << 16), accx);
    accy = fmaf(nm.x, __uint_as_float(u0 & 0xffff0000u), accy);
    accx = fmaf(nm.y, __uint_as_float(u1 << 16), accx);
    accy = fmaf(nm.y, __uint_as_float(u1 & 0xffff0000u), accy);
    accx = fmaf(nm.z, __uint_as_float(u2 << 16), accx);
    accy = fmaf(nm.z, __uint_as_float(u2 & 0xffff0000u), accy);
    accx = fmaf(nm.w, __uint_as_float(u3 << 16), accx);
    accy = fmaf(nm.w, __uint_as_float(u3 & 0xffff0000u), accy);
  }
  for (; idx < e; idx++) {
    int src = src_s[idx];
    float nm = norm_s[idx];
    uint u = xw[(size_t)src * 64 + lane];
    accx = fmaf(nm, __uint_as_float(u << 16), accx);
    accy = fmaf(nm, __uint_as_float(u & 0xffff0000u), accy);
  }
  // self-loop
  float dd = dis[node];
  dd = dd * dd;
  {
    uint u = xw[(size_t)node * 64 + lane];
    accx = fmaf(dd, __uint_as_float(u << 16), accx);
    accy = fmaf(dd, __uint_as_float(u & 0xffff0000u), accy);
  }
  float2 b = ((const float2*)bias)[lane];
  accx += b.x;
  accy += b.y;
  if (relu) {
    accx = fmaxf(accx, 0.f);
    accy = fmaxf(accy, 0.f);
  }
  ((float2*)out)[(size_t)node * 64 + lane] = make_float2(accx, accy);
}

// ---------------- small-M GEMM: out[64][N] += A[64][K] * W[N][K]^T, k-split ----------------

__global__ __launch_bounds__(256) void biasinit(float* __restrict__ out,
                                                const float* __restrict__ bias, int N) {
  int idx = blockIdx.x * 256 + threadIdx.x;
  if (idx < 64 * N) out[idx] = bias[idx % N];
}

__global__ __launch_bounds__(256) void gemm64(const float* __restrict__ A,
                                              const float* __restrict__ W,
                                              float* __restrict__ out, int N, int K,
                                              int kChunk) {
  __shared__ float xs[16][68];  // [k][m]
  __shared__ float ws[16][68];  // [k][n]
  int t = threadIdx.x;
  int n0 = blockIdx.x * 64;
  int k0 = blockIdx.y * kChunk;
  int kEnd = min(K, k0 + kChunk);
  int tn = t & 15;  // n = n0 + tn*4 + ni
  int tm = t >> 4;  // m = tm*4 + mi
  float acc[4][4] = {};
  for (int kt = k0; kt < kEnd; kt += 16) {
    int kc = (t & 3) * 4;
    int rr = t >> 2;  // 0..63
    float4 va = *(const float4*)(A + (size_t)rr * K + kt + kc);
    xs[kc + 0][rr] = va.x; xs[kc + 1][rr] = va.y; xs[kc + 2][rr] = va.z; xs[kc + 3][rr] = va.w;
    float4 vw = *(const float4*)(W + (size_t)(n0 + rr) * K + kt + kc);
    ws[kc + 0][rr] = vw.x; ws[kc + 1][rr] = vw.y; ws[kc + 2][rr] = vw.z; ws[kc + 3][rr] = vw.w;
    __syncthreads();
    #pragma unroll
    for (int k = 0; k < 16; k++) {
      float4 xv = *(const float4*)&xs[k][tm * 4];
      float4 wv = *(const float4*)&ws[k][tn * 4];
      float xm[4] = {xv.x, xv.y, xv.z, xv.w};
      float wn[4] = {wv.x, wv.y, wv.z, wv.w};
      #pragma unroll
      for (int mi = 0; mi < 4; mi++)
        #pragma unroll
        for (int ni = 0; ni < 4; ni++)
          acc[mi][ni] = fmaf(xm[mi], wn[ni], acc[mi][ni]);
    }
    __syncthreads();
  }
  #pragma unroll
  for (int mi = 0; mi < 4; mi++)
    #pragma unroll
    for (int ni = 0; ni < 4; ni++)
      atomicAdd(&out[(size_t)(tm * 4 + mi) * N + n0 + tn * 4 + ni], acc[mi][ni]);
}

// ---------------- pooling + heads ----------------

__global__ void graph_bounds(const int* __restrict__ batch, int* __restrict__ goff) {
  int g = threadIdx.x;
  if (g <= NG) {
    int lo = 0, hi = NN;
    while (lo < hi) {
      int mid = (lo + hi) >> 1;
      if (batch[mid] < g) lo = mid + 1; else hi = mid;
    }
    goff[g] = lo;
  }
}

__global__ __launch_bounds__(128) void pool_partial(const float* __restrict__ xg,
                                                    const int* __restrict__ goff,
                                                    float* __restrict__ pooled) {
  int g = blockIdx.x;
  int chunk = blockIdx.y;  // 0..7
  int t = threadIdx.x;
  int s = goff[g], e = goff[g + 1];
  float acc = 0.f;
  for (int i = s + chunk; i < e; i += 8) acc += xg[(size_t)i * D + t];
  atomicAdd(&pooled[g * D + t], acc);
}

__global__ __launch_bounds__(128) void pool_finish(float* __restrict__ pooled,
                                                   const int* __restrict__ goff) {
  int g = blockIdx.x;
  int t = threadIdx.x;
  int c = goff[g + 1] - goff[g];
  pooled[g * D + t] /= fmaxf((float)c, 1.0f);
}

__global__ __launch_bounds__(256) void build_xcat(const float* __restrict__ xi,
                                                  const float* __restrict__ pooled,
                                                  float* __restrict__ xcat) {
  int idx = blockIdx.x * 256 + threadIdx.x;  // 64 * 1056 float4s
  if (idx < 64 * 1056) {
    int r = idx / 1056;
    int c = idx % 1056;
    float4 v = (c < 1024) ? ((const float4*)xi)[r * 1024 + c]
                          : ((const float4*)pooled)[r * 32 + (c - 1024)];
    ((float4*)xcat)[idx] = v;
  }
}

__global__ __launch_bounds__(128) void normalize_rows(const float* __restrict__ oi_raw,
                                                      const float* __restrict__ oc_raw,
                                                      float* __restrict__ out) {
  int r = blockIdx.x;  // 0..127; 0..63 -> oi, 64..127 -> oc
  int t = threadIdx.x;
  const float* src = (r < 64) ? (oi_raw + r * D) : (oc_raw + (r - 64) * D);
  float v = src[t];
  __shared__ float red[128];
  red[t] = v * v;
  __syncthreads();
  for (int s = 64; s > 0; s >>= 1) {
    if (t < s) red[t] += red[t + s];
    __syncthreads();
  }
  out[r * D + t] = v / sqrtf(red[0]);
}

// ---------------- launch ----------------

extern "C" void kernel_launch(void* const* d_in, const int* in_sizes, int n_in,
                              void* d_out, int out_size, void* d_ws, size_t ws_size,
                              hipStream_t stream) {
  const float* images = (const float*)d_in[0];
  const int* node_types = (const int*)d_in[1];
  const int* erow = (const int*)d_in[2];
  const int* ecol = erow + NE;
  const float* eattr = (const float*)d_in[3];
  const int* batch = (const int*)d_in[4];
  const float* emb = (const float*)d_in[5];
  const float* W_img = (const float*)d_in[6];
  const float* b_img = (const float*)d_in[7];
  const float* W1 = (const float*)d_in[8];
  const float* b1 = (const float*)d_in[9];
  const float* W2 = (const float*)d_in[10];
  const float* b2 = (const float*)d_in[11];
  const float* W3 = (const float*)d_in[12];
  const float* b3 = (const float*)d_in[13];
  const float* Wi = (const float*)d_in[14];
  const float* bi = (const float*)d_in[15];
  const float* Wc = (const float*)d_in[16];
  const float* bc = (const float*)d_in[17];
  float* out = (float*)d_out;

  // workspace carve (512B aligned)
  char* w = (char*)d_ws;
  auto alloc = [&](size_t bytes) -> void* {
    void* p = (void*)w;
    w += (bytes + 511) & ~(size_t)511;
    return p;
  };
  float* deg = (float*)alloc(NN * 4);
  int* cnt_i = (int*)alloc(NN * 4);
  int* wcur = (int*)alloc(NN * 4);
  float* pooled = (float*)alloc(64 * D * 4);
  size_t zero_bytes = (size_t)(w - (char*)d_ws);  // deg+cnt+wcur+pooled need zeroing
  int* csr_off = (int*)alloc((NN + 1) * 4);
  int* goff = (int*)alloc((NG + 1) * 4);
  int* scan_incl = (int*)alloc(NN * 4);
  int* scan_part = (int*)alloc(SCAN_BLOCKS * 4);
  int* src_s = (int*)alloc((size_t)NE * 4);
  float* norm_s = (float*)alloc((size_t)NE * 4);
  float* dis = (float*)alloc(NN * 4);
  float* bufA = (float*)alloc((size_t)NN * D * 4);
  uint* bufB = (uint*)alloc((size_t)NN * D * 2);  // bf16 xw
  float* xi = (float*)alloc((size_t)64 * IMG * 4);
  float* xcat = (float*)alloc((size_t)64 * (IMG + D) * 4);
  float* oi_raw = (float*)alloc(64 * D * 4);
  float* oc_raw = (float*)alloc(64 * D * 4);

  hipMemsetAsync(d_ws, 0, zero_bytes, stream);

  // graph preprocessing
  edge_pass1<<<NE / 256, 256, 0, stream>>>(ecol, eattr, deg, cnt_i);
  dis_kernel<<<(NN + 255) / 256, 256, 0, stream>>>(deg, dis);
  scan_blocks<<<SCAN_BLOCKS, 256, 0, stream>>>(cnt_i, scan_incl, scan_part);
  scan_partials<<<1, 256, 0, stream>>>(scan_part, SCAN_BLOCKS);
  scan_apply<<<SCAN_BLOCKS, 256, 0, stream>>>(scan_incl, scan_part, csr_off);
  fill_kernel<<<NE / 256, 256, 0, stream>>>(erow, ecol, eattr, dis, csr_off, wcur, src_s,
                                            norm_s);
  gather_emb<<<NN * 32 / 256, 256, 0, stream>>>(node_types, emb, bufA);

  // 3 GCN convs
  int nblk = (NN + 63) / 64;
  node_gemm<<<nblk, 256, 0, stream>>>(bufA, W1, bufB);
  aggregate<<<(NN + 3) / 4, 256, 0, stream>>>(bufB, bufA, csr_off, src_s, norm_s, dis, b1, 1);
  node_gemm<<<nblk, 256, 0, stream>>>(bufA, W2, bufB);
  aggregate<<<(NN + 3) / 4, 256, 0, stream>>>(bufB, bufA, csr_off, src_s, norm_s, dis, b2, 1);
  node_gemm<<<nblk, 256, 0, stream>>>(bufA, W3, bufB);
  aggregate<<<(NN + 3) / 4, 256, 0, stream>>>(bufB, bufA, csr_off, src_s, norm_s, dis, b3, 0);

  // pooling
  graph_bounds<<<1, 128, 0, stream>>>(batch, goff);
  {
    dim3 g(NG, 8);
    pool_partial<<<g, 128, 0, stream>>>(bufA, goff, pooled);
  }
  pool_finish<<<NG, 128, 0, stream>>>(pooled, goff);

  // image path: xi = images @ W_img.T + b_img
  biasinit<<<(64 * IMG + 255) / 256, 256, 0, stream>>>(xi, b_img, IMG);
  {
    dim3 g(IMG / 64, 8);
    gemm64<<<g, 256, 0, stream>>>(images, W_img, xi, IMG, IMG, 512);
  }
  // oi = normalize(xi @ Wi.T + bi)
  biasinit<<<(64 * D + 255) / 256, 256, 0, stream>>>(oi_raw, bi, D);
  {
    dim3 g(D / 64, 32);
    gemm64<<<g, 256, 0, stream>>>(xi, Wi, oi_raw, D, IMG, 128);
  }
  // oc = normalize(concat(xi, pooled) @ Wc.T + bc)
  build_xcat<<<(64 * 1056 + 255) / 256, 256, 0, stream>>>(xi, pooled, xcat);
  biasinit<<<(64 * D + 255) / 256, 256, 0, stream>>>(oc_raw, bc, D);
  {
    dim3 g(D / 64, 24);
    gemm64<<<g, 256, 0, stream>>>(xcat, Wc, oc_raw, D, IMG + D, 176);
  }
  normalize_rows<<<128, 128, 0, stream>>>(oi_raw, oc_raw, out);
}

// Round 4
// 582.054 us; speedup vs baseline: 1.4835x; 1.1025x over previous
//
#include <hip/hip_runtime.h>
#include <math.h>

#define NN 50000
#define NE 800000
#define NG 64
#define D 128
#define IMG 4096
#define SCAN_BLOCKS ((NN + 255) / 256)

typedef unsigned int uint;

// bf16 helpers (bit-level, RNE pack / shift unpack)
__device__ __forceinline__ uint bf16rne(float f) {
  uint h = __float_as_uint(f);
  return (h + 0x7fffu + ((h >> 16) & 1u)) >> 16;
}
__device__ __forceinline__ uint pack2bf(float a, float b) {
  return bf16rne(a) | (bf16rne(b) << 16);
}

// ---------------- graph preprocessing ----------------

// pass 1: count in-edges per node; atomic return value IS the CSR slot
__global__ void edge_slot(const int* __restrict__ col, int* __restrict__ cnt,
                          int* __restrict__ slot) {
  int e = blockIdx.x * 256 + threadIdx.x;
  if (e < NE) {
    int c = col[e];
    slot[e] = atomicAdd(&cnt[c], 1);
  }
}

// ---- 3-level parallel exclusive scan of cnt[NN] -> off[NN+1] ----

__global__ __launch_bounds__(256) void scan_blocks(const int* __restrict__ cnt,
                                                   int* __restrict__ incl,
                                                   int* __restrict__ partial) {
  __shared__ int sd[256];
  int t = threadIdx.x;
  int i = blockIdx.x * 256 + t;
  int v = (i < NN) ? cnt[i] : 0;
  sd[t] = v;
  __syncthreads();
  #pragma unroll
  for (int s = 1; s < 256; s <<= 1) {
    int add = (t >= s) ? sd[t - s] : 0;
    __syncthreads();
    sd[t] += add;
    __syncthreads();
  }
  if (i < NN) incl[i] = sd[t];
  if (t == 255) partial[blockIdx.x] = sd[255];
}

__global__ __launch_bounds__(256) void scan_partials(int* __restrict__ partial, int nb) {
  __shared__ int sd[256];
  int t = threadIdx.x;
  int v = (t < nb) ? partial[t] : 0;
  sd[t] = v;
  __syncthreads();
  #pragma unroll
  for (int s = 1; s < 256; s <<= 1) {
    int add = (t >= s) ? sd[t - s] : 0;
    __syncthreads();
    sd[t] += add;
    __syncthreads();
  }
  if (t < nb) partial[t] = (t == 0) ? 0 : sd[t - 1];
}

__global__ __launch_bounds__(256) void scan_apply(const int* __restrict__ incl,
                                                  const int* __restrict__ partial,
                                                  int* __restrict__ off) {
  int i = blockIdx.x * 256 + threadIdx.x;
  if (i < NN) off[i + 1] = incl[i] + partial[blockIdx.x];
  if (i == 0) off[0] = 0;
}

// pass 2: atomic-free scatter into CSR
__global__ void fill_scatter(const int* __restrict__ row, const int* __restrict__ col,
                             const float* __restrict__ ew, const int* __restrict__ off,
                             const int* __restrict__ slot, int* __restrict__ src_s,
                             float* __restrict__ ew_s) {
  int e = blockIdx.x * 256 + threadIdx.x;
  if (e < NE) {
    int idx = off[col[e]] + slot[e];
    src_s[idx] = row[e];
    ew_s[idx] = ew[e];
  }
}

// segmented sum of ew per node -> dis = rsqrt(deg+1)
__global__ void deg_csr(const int* __restrict__ off, const float* __restrict__ ew_s,
                        float* __restrict__ dis) {
  int i = blockIdx.x * 256 + threadIdx.x;
  if (i < NN) {
    int s = off[i], e = off[i + 1];
    float acc = 0.f;
    for (int j = s; j < e; j++) acc += ew_s[j];
    dis[i] = 1.0f / sqrtf(acc + 1.0f);
  }
}

// norm_s[idx] = dis[src] * ew * dis[c]
__global__ void norm_fill(const int* __restrict__ off, const int* __restrict__ src_s,
                          const float* __restrict__ ew_s, const float* __restrict__ dis,
                          float* __restrict__ norm_s) {
  int i = blockIdx.x * 256 + threadIdx.x;
  if (i < NN) {
    int s = off[i], e = off[i + 1];
    float dc = dis[i];
    for (int j = s; j < e; j++) norm_s[j] = dis[src_s[j]] * ew_s[j] * dc;
  }
}

__global__ void gather_emb(const int* __restrict__ types, const float* __restrict__ emb,
                           float* __restrict__ x) {
  int tid = blockIdx.x * 256 + threadIdx.x;  // NN*32 threads, float4 each
  int i = tid >> 5;
  int j = tid & 31;
  if (i < NN) ((float4*)x)[i * 32 + j] = ((const float4*)emb)[types[i] * 32 + j];
}

// ---------------- node GEMM: out[i][n] = sum_k x[i][k] * W[n][k], K=D=128 ----------------
// Output packed bf16 (RNE) for the aggregation gather.

__global__ __launch_bounds__(256) void node_gemm(const float* __restrict__ x,
                                                 const float* __restrict__ W,
                                                 uint* __restrict__ outbf) {
  __shared__ float xs[16][68];   // [k][m]
  __shared__ float ws[16][132];  // [k][n]
  int t = threadIdx.x;
  int m0 = blockIdx.x * 64;
  int tm = t >> 4;  // 0..15 -> m = m0 + tm*4 + mi
  int tn = t & 15;  // 0..15 -> n = tn*8 + nj
  float acc[4][8] = {};
  for (int kt = 0; kt < D; kt += 16) {
    {  // stage x tile [64 m x 16 k] transposed
      int mm = m0 + (t >> 2);
      int kc = (t & 3) * 4;
      float4 v = make_float4(0.f, 0.f, 0.f, 0.f);
      if (mm < NN) v = *(const float4*)(x + (size_t)mm * D + kt + kc);
      int ml = t >> 2;
      xs[kc + 0][ml] = v.x; xs[kc + 1][ml] = v.y; xs[kc + 2][ml] = v.z; xs[kc + 3][ml] = v.w;
    }
    {  // stage W tile [128 n x 16 k] transposed
      int kc = (t & 3) * 4;
      #pragma unroll
      for (int r = 0; r < 2; r++) {
        int nn = (t >> 2) + r * 64;
        float4 v = *(const float4*)(W + (size_t)nn * D + kt + kc);
        ws[kc + 0][nn] = v.x; ws[kc + 1][nn] = v.y; ws[kc + 2][nn] = v.z; ws[kc + 3][nn] = v.w;
      }
    }
    __syncthreads();
    #pragma unroll
    for (int k = 0; k < 16; k++) {
      float4 xv = *(const float4*)&xs[k][tm * 4];
      float4 wa = *(const float4*)&ws[k][tn * 8];
      float4 wb = *(const float4*)&ws[k][tn * 8 + 4];
      float xm[4] = {xv.x, xv.y, xv.z, xv.w};
      float wn[8] = {wa.x, wa.y, wa.z, wa.w, wb.x, wb.y, wb.z, wb.w};
      #pragma unroll
      for (int mi = 0; mi < 4; mi++)
        #pragma unroll
        for (int nj = 0; nj < 8; nj++)
          acc[mi][nj] = fmaf(xm[mi], wn[nj], acc[mi][nj]);
    }
    __syncthreads();
  }
  #pragma unroll
  for (int mi = 0; mi < 4; mi++) {
    int mm = m0 + tm * 4 + mi;
    if (mm < NN) {
      uint4 o;
      o.x = pack2bf(acc[mi][0], acc[mi][1]);
      o.y = pack2bf(acc[mi][2], acc[mi][3]);
      o.z = pack2bf(acc[mi][4], acc[mi][5]);
      o.w = pack2bf(acc[mi][6], acc[mi][7]);
      *(uint4*)(outbf + (size_t)mm * 64 + tn * 4) = o;  // 64 uints per row (128 bf16)
    }
  }
}

// ---------------- CSR aggregation: one wave per node, bf16 gather, 8x MLP ----------------

__global__ __launch_bounds__(256) void aggregate(const uint* __restrict__ xw,
                                                 float* __restrict__ out,
                                                 const int* __restrict__ off,
                                                 const int* __restrict__ src_s,
                                                 const float* __restrict__ norm_s,
                                                 const float* __restrict__ dis,
                                                 const float* __restrict__ bias, int relu) {
  int wave = threadIdx.x >> 6;
  int lane = threadIdx.x & 63;
  int node = blockIdx.x * 4 + wave;
  if (node >= NN) return;
  float accx = 0.f, accy = 0.f;
  int s = off[node], e = off[node + 1];
  int idx = s;
  int astart = (s + 3) & ~3;
  if (astart > e) astart = e;
  for (; idx < astart; idx++) {
    int src = src_s[idx];
    float nm = norm_s[idx];
    uint u = xw[(size_t)src * 64 + lane];
    accx = fmaf(nm, __uint_as_float(u << 16), accx);
    accy = fmaf(nm, __uint_as_float(u & 0xffff0000u), accy);
  }
  for (; idx + 8 <= e; idx += 8) {
    int4 sa = *(const int4*)(src_s + idx);
    int4 sb = *(const int4*)(src_s + idx + 4);
    float4 na = *(const float4*)(norm_s + idx);
    float4 nb = *(const float4*)(norm_s + idx + 4);
    uint u0 = xw[(size_t)sa.x * 64 + lane];
    uint u1 = xw[(size_t)sa.y * 64 + lane];
    uint u2 = xw[(size_t)sa.z * 64 + lane];
    uint u3 = xw[(size_t)sa.w * 64 + lane];
    uint u4 = xw[(size_t)sb.x * 64 + lane];
    uint u5 = xw[(size_t)sb.y * 64 + lane];
    uint u6 = xw[(size_t)sb.z * 64 + lane];
    uint u7 = xw[(size_t)sb.w * 64 + lane];
    accx = fmaf(na.x, __uint_as_float(u0 << 16), accx);
    accy = fmaf(na.x, __uint_as_float(u0 & 0xffff0000u), accy);
    accx = fmaf(na.y, __uint_as_float(u1 << 16), accx);
    accy = fmaf(na.y, __uint_as_float(u1 & 0xffff0000u), accy);
    accx = fmaf(na.z, __uint_as_float(u2 << 16), accx);
    accy = fmaf(na.z, __uint_as_float(u2 & 0xffff0000u), accy);
    accx = fmaf(na.w, __uint_as_float(u3 << 16), accx);
    accy = fmaf(na.w, __uint_as_float(u3 & 0xffff0000u), accy);
    accx = fmaf(nb.x, __uint_as_float(u4 << 16), accx);
    accy = fmaf(nb.x, __uint_as_float(u4 & 0xffff0000u), accy);
    accx = fmaf(nb.y, __uint_as_float(u5 << 16), accx);
    accy = fmaf(nb.y, __uint_as_float(u5 & 0xffff0000u), accy);
    accx = fmaf(nb.z, __uint_as_float(u6 << 16), accx);
    accy = fmaf(nb.z, __uint_as_float(u6 & 0xffff0000u), accy);
    accx = fmaf(nb.w, __uint_as_float(u7 << 16), accx);
    accy = fmaf(nb.w, __uint_as_float(u7 & 0xffff0000u), accy);
  }
  for (; idx + 4 <= e; idx += 4) {
    int4 sr = *(const int4*)(src_s + idx);
    float4 nm = *(const float4*)(norm_s + idx);
    uint u0 = xw[(size_t)sr.x * 64 + lane];
    uint u1 = xw[(size_t)sr.y * 64 + lane];
    uint u2 = xw[(size_t)sr.z * 64 + lane];
    uint u3 = xw[(size_t)sr.w * 64 + lane];
    accx = fmaf(nm.x, __uint_as_float(u0 << 16), accx);
    accy = fmaf(nm.x, __uint_as_float(u0 & 0xffff0000u), accy);
    accx = fmaf(nm.y, __uint_as_float(u1 << 16), accx);
    accy = fmaf(nm.y, __uint_as_float(u1 & 0xffff0000u), accy);
    accx = fmaf(nm.z, __uint_as_float(u2 << 16), accx);
    accy = fmaf(nm.z, __uint_as_float(u2 & 0xffff0000u), accy);
    accx = fmaf(nm.w, __uint_as_float(u3 << 16), accx);
    accy = fmaf(nm.w, __uint_as_float(u3 & 0xffff0000u), accy);
  }
  for (; idx < e; idx++) {
    int src = src_s[idx];
    float nm = norm_s[idx];
    uint u = xw[(size_t)src * 64 + lane];
    accx = fmaf(nm, __uint_as_float(u << 16), accx);
    accy = fmaf(nm, __uint_as_float(u & 0xffff0000u), accy);
  }
  // self-loop
  float dd = dis[node];
  dd = dd * dd;
  {
    uint u = xw[(size_t)node * 64 + lane];
    accx = fmaf(dd, __uint_as_float(u << 16), accx);
    accy = fmaf(dd, __uint_as_float(u & 0xffff0000u), accy);
  }
  float2 b = ((const float2*)bias)[lane];
  accx += b.x;
  accy += b.y;
  if (relu) {
    accx = fmaxf(accx, 0.f);
    accy = fmaxf(accy, 0.f);
  }
  ((float2*)out)[(size_t)node * 64 + lane] = make_float2(accx, accy);
}

// ---------------- small-M GEMM: out[64][N] += A[64][K] * W[N][K]^T, k-split ----------------

__global__ __launch_bounds__(256) void biasinit(float* __restrict__ out,
                                                const float* __restrict__ bias, int N) {
  int idx = blockIdx.x * 256 + threadIdx.x;
  if (idx < 64 * N) out[idx] = bias[idx % N];
}

__global__ __launch_bounds__(256) void gemm64(const float* __restrict__ A,
                                              const float* __restrict__ W,
                                              float* __restrict__ out, int N, int K,
                                              int kChunk) {
  __shared__ float xs[16][68];  // [k][m]
  __shared__ float ws[16][68];  // [k][n]
  int t = threadIdx.x;
  int n0 = blockIdx.x * 64;
  int k0 = blockIdx.y * kChunk;
  int kEnd = min(K, k0 + kChunk);
  int tn = t & 15;  // n = n0 + tn*4 + ni
  int tm = t >> 4;  // m = tm*4 + mi
  float acc[4][4] = {};
  for (int kt = k0; kt < kEnd; kt += 16) {
    int kc = (t & 3) * 4;
    int rr = t >> 2;  // 0..63
    float4 va = *(const float4*)(A + (size_t)rr * K + kt + kc);
    xs[kc + 0][rr] = va.x; xs[kc + 1][rr] = va.y; xs[kc + 2][rr] = va.z; xs[kc + 3][rr] = va.w;
    float4 vw = *(const float4*)(W + (size_t)(n0 + rr) * K + kt + kc);
    ws[kc + 0][rr] = vw.x; ws[kc + 1][rr] = vw.y; ws[kc + 2][rr] = vw.z; ws[kc + 3][rr] = vw.w;
    __syncthreads();
    #pragma unroll
    for (int k = 0; k < 16; k++) {
      float4 xv = *(const float4*)&xs[k][tm * 4];
      float4 wv = *(const float4*)&ws[k][tn * 4];
      float xm[4] = {xv.x, xv.y, xv.z, xv.w};
      float wn[4] = {wv.x, wv.y, wv.z, wv.w};
      #pragma unroll
      for (int mi = 0; mi < 4; mi++)
        #pragma unroll
        for (int ni = 0; ni < 4; ni++)
          acc[mi][ni] = fmaf(xm[mi], wn[ni], acc[mi][ni]);
    }
    __syncthreads();
  }
  #pragma unroll
  for (int mi = 0; mi < 4; mi++)
    #pragma unroll
    for (int ni = 0; ni < 4; ni++)
      atomicAdd(&out[(size_t)(tm * 4 + mi) * N + n0 + tn * 4 + ni], acc[mi][ni]);
}

// ---------------- pooling + heads ----------------

__global__ void graph_bounds(const int* __restrict__ batch, int* __restrict__ goff) {
  int g = threadIdx.x;
  if (g <= NG) {
    int lo = 0, hi = NN;
    while (lo < hi) {
      int mid = (lo + hi) >> 1;
      if (batch[mid] < g) lo = mid + 1; else hi = mid;
    }
    goff[g] = lo;
  }
}

__global__ __launch_bounds__(128) void pool_partial(const float* __restrict__ xg,
                                                    const int* __restrict__ goff,
                                                    float* __restrict__ pooled) {
  int g = blockIdx.x;
  int chunk = blockIdx.y;  // 0..7
  int t = threadIdx.x;
  int s = goff[g], e = goff[g + 1];
  float acc = 0.f;
  for (int i = s + chunk; i < e; i += 8) acc += xg[(size_t)i * D + t];
  atomicAdd(&pooled[g * D + t], acc);
}

__global__ __launch_bounds__(128) void pool_finish(float* __restrict__ pooled,
                                                   const int* __restrict__ goff) {
  int g = blockIdx.x;
  int t = threadIdx.x;
  int c = goff[g + 1] - goff[g];
  pooled[g * D + t] /= fmaxf((float)c, 1.0f);
}

__global__ __launch_bounds__(256) void build_xcat(const float* __restrict__ xi,
                                                  const float* __restrict__ pooled,
                                                  float* __restrict__ xcat) {
  int idx = blockIdx.x * 256 + threadIdx.x;  // 64 * 1056 float4s
  if (idx < 64 * 1056) {
    int r = idx / 1056;
    int c = idx % 1056;
    float4 v = (c < 1024) ? ((const float4*)xi)[r * 1024 + c]
                          : ((const float4*)pooled)[r * 32 + (c - 1024)];
    ((float4*)xcat)[idx] = v;
  }
}

__global__ __launch_bounds__(128) void normalize_rows(const float* __restrict__ oi_raw,
                                                      const float* __restrict__ oc_raw,
                                                      float* __restrict__ out) {
  int r = blockIdx.x;  // 0..127; 0..63 -> oi, 64..127 -> oc
  int t = threadIdx.x;
  const float* src = (r < 64) ? (oi_raw + r * D) : (oc_raw + (r - 64) * D);
  float v = src[t];
  __shared__ float red[128];
  red[t] = v * v;
  __syncthreads();
  for (int s = 64; s > 0; s >>= 1) {
    if (t < s) red[t] += red[t + s];
    __syncthreads();
  }
  out[r * D + t] = v / sqrtf(red[0]);
}

// ---------------- launch ----------------

extern "C" void kernel_launch(void* const* d_in, const int* in_sizes, int n_in,
                              void* d_out, int out_size, void* d_ws, size_t ws_size,
                              hipStream_t stream) {
  const float* images = (const float*)d_in[0];
  const int* node_types = (const int*)d_in[1];
  const int* erow = (const int*)d_in[2];
  const int* ecol = erow + NE;
  const float* eattr = (const float*)d_in[3];
  const int* batch = (const int*)d_in[4];
  const float* emb = (const float*)d_in[5];
  const float* W_img = (const float*)d_in[6];
  const float* b_img = (const float*)d_in[7];
  const float* W1 = (const float*)d_in[8];
  const float* b1 = (const float*)d_in[9];
  const float* W2 = (const float*)d_in[10];
  const float* b2 = (const float*)d_in[11];
  const float* W3 = (const float*)d_in[12];
  const float* b3 = (const float*)d_in[13];
  const float* Wi = (const float*)d_in[14];
  const float* bi = (const float*)d_in[15];
  const float* Wc = (const float*)d_in[16];
  const float* bc = (const float*)d_in[17];
  float* out = (float*)d_out;

  // workspace carve (512B aligned)
  char* w = (char*)d_ws;
  auto alloc = [&](size_t bytes) -> void* {
    void* p = (void*)w;
    w += (bytes + 511) & ~(size_t)511;
    return p;
  };
  int* cnt_i = (int*)alloc(NN * 4);
  float* pooled = (float*)alloc(64 * D * 4);
  size_t zero_bytes = (size_t)(w - (char*)d_ws);  // cnt + pooled need zeroing
  int* csr_off = (int*)alloc((NN + 1) * 4);
  int* goff = (int*)alloc((NG + 1) * 4);
  int* scan_incl = (int*)alloc(NN * 4);
  int* scan_part = (int*)alloc(SCAN_BLOCKS * 4);
  int* slot = (int*)alloc((size_t)NE * 4);
  int* src_s = (int*)alloc((size_t)NE * 4);
  float* ew_s = (float*)alloc((size_t)NE * 4);
  float* norm_s = (float*)alloc((size_t)NE * 4);
  float* dis = (float*)alloc(NN * 4);
  float* bufA = (float*)alloc((size_t)NN * D * 4);
  uint* bufB = (uint*)alloc((size_t)NN * D * 2);  // bf16 xw
  float* xi = (float*)alloc((size_t)64 * IMG * 4);
  float* xcat = (float*)alloc((size_t)64 * (IMG + D) * 4);
  float* oi_raw = (float*)alloc(64 * D * 4);
  float* oc_raw = (float*)alloc(64 * D * 4);

  hipMemsetAsync(d_ws, 0, zero_bytes, stream);

  // graph preprocessing (single per-edge atomic pass; fill is atomic-free)
  edge_slot<<<NE / 256, 256, 0, stream>>>(ecol, cnt_i, slot);
  scan_blocks<<<SCAN_BLOCKS, 256, 0, stream>>>(cnt_i, scan_incl, scan_part);
  scan_partials<<<1, 256, 0, stream>>>(scan_part, SCAN_BLOCKS);
  scan_apply<<<SCAN_BLOCKS, 256, 0, stream>>>(scan_incl, scan_part, csr_off);
  fill_scatter<<<NE / 256, 256, 0, stream>>>(erow, ecol, eattr, csr_off, slot, src_s, ew_s);
  deg_csr<<<(NN + 255) / 256, 256, 0, stream>>>(csr_off, ew_s, dis);
  norm_fill<<<(NN + 255) / 256, 256, 0, stream>>>(csr_off, src_s, ew_s, dis, norm_s);
  gather_emb<<<NN * 32 / 256, 256, 0, stream>>>(node_types, emb, bufA);

  // 3 GCN convs
  int nblk = (NN + 63) / 64;
  node_gemm<<<nblk, 256, 0, stream>>>(bufA, W1, bufB);
  aggregate<<<(NN + 3) / 4, 256, 0, stream>>>(bufB, bufA, csr_off, src_s, norm_s, dis, b1, 1);
  node_gemm<<<nblk, 256, 0, stream>>>(bufA, W2, bufB);
  aggregate<<<(NN + 3) / 4, 256, 0, stream>>>(bufB, bufA, csr_off, src_s, norm_s, dis, b2, 1);
  node_gemm<<<nblk, 256, 0, stream>>>(bufA, W3, bufB);
  aggregate<<<(NN + 3) / 4, 256, 0, stream>>>(bufB, bufA, csr_off, src_s, norm_s, dis, b3, 0);

  // pooling
  graph_bounds<<<1, 128, 0, stream>>>(batch, goff);
  {
    dim3 g(NG, 8);
    pool_partial<<<g, 128, 0, stream>>>(bufA, goff, pooled);
  }
  pool_finish<<<NG, 128, 0, stream>>>(pooled, goff);

  // image path: xi = images @ W_img.T + b_img
  biasinit<<<(64 * IMG + 255) / 256, 256, 0, stream>>>(xi, b_img, IMG);
  {
    dim3 g(IMG / 64, 8);
    gemm64<<<g, 256, 0, stream>>>(images, W_img, xi, IMG, IMG, 512);
  }
  // oi = normalize(xi @ Wi.T + bi)
  biasinit<<<(64 * D + 255) / 256, 256, 0, stream>>>(oi_raw, bi, D);
  {
    dim3 g(D / 64, 32);
    gemm64<<<g, 256, 0, stream>>>(xi, Wi, oi_raw, D, IMG, 128);
  }
  // oc = normalize(concat(xi, pooled) @ Wc.T + bc)
  build_xcat<<<(64 * 1056 + 255) / 256, 256, 0, stream>>>(xi, pooled, xcat);
  biasinit<<<(64 * D + 255) / 256, 256, 0, stream>>>(oc_raw, bc, D);
  {
    dim3 g(D / 64, 24);
    gemm64<<<g, 256, 0, stream>>>(xcat, Wc, oc_raw, D, IMG + D, 176);
  }
  normalize_rows<<<128, 128, 0, stream>>>(oi_raw, oc_raw, out);
}

// Round 5
// 552.915 us; speedup vs baseline: 1.5616x; 1.0527x over previous
//
#include <hip/hip_runtime.h>
#include <math.h>

#define NN 50000
#define NE 800000
#define NG 64
#define D 128
#define IMG 4096
#define SCAN_BLOCKS ((NN + 255) / 256)

typedef unsigned int uint;
typedef __attribute__((ext_vector_type(8))) __bf16 bf16x8;
typedef __attribute__((ext_vector_type(4))) float f32x4;

// bf16 helpers (bit-level, RNE pack / shift unpack)
__device__ __forceinline__ uint bf16rne(float f) {
  uint h = __float_as_uint(f);
  return (h + 0x7fffu + ((h >> 16) & 1u)) >> 16;
}
__device__ __forceinline__ uint pack2bf(float a, float b) {
  return bf16rne(a) | (bf16rne(b) << 16);
}

// ---------------- graph preprocessing ----------------

// pass 1: count in-edges per node; atomic return value IS the CSR slot
__global__ void edge_slot(const int* __restrict__ col, int* __restrict__ cnt,
                          int* __restrict__ slot) {
  int e = blockIdx.x * 256 + threadIdx.x;
  if (e < NE) {
    int c = col[e];
    slot[e] = atomicAdd(&cnt[c], 1);
  }
}

// ---- 3-level parallel exclusive scan of cnt[NN] -> off[NN+1] ----

__global__ __launch_bounds__(256) void scan_blocks(const int* __restrict__ cnt,
                                                   int* __restrict__ incl,
                                                   int* __restrict__ partial) {
  __shared__ int sd[256];
  int t = threadIdx.x;
  int i = blockIdx.x * 256 + t;
  int v = (i < NN) ? cnt[i] : 0;
  sd[t] = v;
  __syncthreads();
  #pragma unroll
  for (int s = 1; s < 256; s <<= 1) {
    int add = (t >= s) ? sd[t - s] : 0;
    __syncthreads();
    sd[t] += add;
    __syncthreads();
  }
  if (i < NN) incl[i] = sd[t];
  if (t == 255) partial[blockIdx.x] = sd[255];
}

__global__ __launch_bounds__(256) void scan_partials(int* __restrict__ partial, int nb) {
  __shared__ int sd[256];
  int t = threadIdx.x;
  int v = (t < nb) ? partial[t] : 0;
  sd[t] = v;
  __syncthreads();
  #pragma unroll
  for (int s = 1; s < 256; s <<= 1) {
    int add = (t >= s) ? sd[t - s] : 0;
    __syncthreads();
    sd[t] += add;
    __syncthreads();
  }
  if (t < nb) partial[t] = (t == 0) ? 0 : sd[t - 1];
}

__global__ __launch_bounds__(256) void scan_apply(const int* __restrict__ incl,
                                                  const int* __restrict__ partial,
                                                  int* __restrict__ off) {
  int i = blockIdx.x * 256 + threadIdx.x;
  if (i < NN) off[i + 1] = incl[i] + partial[blockIdx.x];
  if (i == 0) off[0] = 0;
}

// pass 2: atomic-free scatter into CSR
__global__ void fill_scatter(const int* __restrict__ row, const int* __restrict__ col,
                             const float* __restrict__ ew, const int* __restrict__ off,
                             const int* __restrict__ slot, int* __restrict__ src_s,
                             float* __restrict__ ew_s) {
  int e = blockIdx.x * 256 + threadIdx.x;
  if (e < NE) {
    int idx = off[col[e]] + slot[e];
    src_s[idx] = row[e];
    ew_s[idx] = ew[e];
  }
}

// segmented sum of ew per node -> dis = rsqrt(deg+1)
__global__ void deg_csr(const int* __restrict__ off, const float* __restrict__ ew_s,
                        float* __restrict__ dis) {
  int i = blockIdx.x * 256 + threadIdx.x;
  if (i < NN) {
    int s = off[i], e = off[i + 1];
    float acc = 0.f;
    for (int j = s; j < e; j++) acc += ew_s[j];
    dis[i] = 1.0f / sqrtf(acc + 1.0f);
  }
}

// norm_s[idx] = dis[src] * ew * dis[c]
__global__ void norm_fill(const int* __restrict__ off, const int* __restrict__ src_s,
                          const float* __restrict__ ew_s, const float* __restrict__ dis,
                          float* __restrict__ norm_s) {
  int i = blockIdx.x * 256 + threadIdx.x;
  if (i < NN) {
    int s = off[i], e = off[i + 1];
    float dc = dis[i];
    for (int j = s; j < e; j++) norm_s[j] = dis[src_s[j]] * ew_s[j] * dc;
  }
}

__global__ void gather_emb(const int* __restrict__ types, const float* __restrict__ emb,
                           float* __restrict__ x) {
  int tid = blockIdx.x * 256 + threadIdx.x;  // NN*32 threads, float4 each
  int i = tid >> 5;
  int j = tid & 31;
  if (i < NN) ((float4*)x)[i * 32 + j] = ((const float4*)emb)[types[i] * 32 + j];
}

// ---------------- node GEMM: out[i][n] = sum_k x[i][k] * W[n][k], K=D=128 ----------------
// Output packed bf16 (RNE) for the aggregation gather.

__global__ __launch_bounds__(256) void node_gemm(const float* __restrict__ x,
                                                 const float* __restrict__ W,
                                                 uint* __restrict__ outbf) {
  __shared__ float xs[16][68];   // [k][m]
  __shared__ float ws[16][132];  // [k][n]
  int t = threadIdx.x;
  int m0 = blockIdx.x * 64;
  int tm = t >> 4;  // 0..15 -> m = m0 + tm*4 + mi
  int tn = t & 15;  // 0..15 -> n = tn*8 + nj
  float acc[4][8] = {};
  for (int kt = 0; kt < D; kt += 16) {
    {  // stage x tile [64 m x 16 k] transposed
      int mm = m0 + (t >> 2);
      int kc = (t & 3) * 4;
      float4 v = make_float4(0.f, 0.f, 0.f, 0.f);
      if (mm < NN) v = *(const float4*)(x + (size_t)mm * D + kt + kc);
      int ml = t >> 2;
      xs[kc + 0][ml] = v.x; xs[kc + 1][ml] = v.y; xs[kc + 2][ml] = v.z; xs[kc + 3][ml] = v.w;
    }
    {  // stage W tile [128 n x 16 k] transposed
      int kc = (t & 3) * 4;
      #pragma unroll
      for (int r = 0; r < 2; r++) {
        int nn = (t >> 2) + r * 64;
        float4 v = *(const float4*)(W + (size_t)nn * D + kt + kc);
        ws[kc + 0][nn] = v.x; ws[kc + 1][nn] = v.y; ws[kc + 2][nn] = v.z; ws[kc + 3][nn] = v.w;
      }
    }
    __syncthreads();
    #pragma unroll
    for (int k = 0; k < 16; k++) {
      float4 xv = *(const float4*)&xs[k][tm * 4];
      float4 wa = *(const float4*)&ws[k][tn * 8];
      float4 wb = *(const float4*)&ws[k][tn * 8 + 4];
      float xm[4] = {xv.x, xv.y, xv.z, xv.w};
      float wn[8] = {wa.x, wa.y, wa.z, wa.w, wb.x, wb.y, wb.z, wb.w};
      #pragma unroll
      for (int mi = 0; mi < 4; mi++)
        #pragma unroll
        for (int nj = 0; nj < 8; nj++)
          acc[mi][nj] = fmaf(xm[mi], wn[nj], acc[mi][nj]);
    }
    __syncthreads();
  }
  #pragma unroll
  for (int mi = 0; mi < 4; mi++) {
    int mm = m0 + tm * 4 + mi;
    if (mm < NN) {
      uint4 o;
      o.x = pack2bf(acc[mi][0], acc[mi][1]);
      o.y = pack2bf(acc[mi][2], acc[mi][3]);
      o.z = pack2bf(acc[mi][4], acc[mi][5]);
      o.w = pack2bf(acc[mi][6], acc[mi][7]);
      *(uint4*)(outbf + (size_t)mm * 64 + tn * 4) = o;  // 64 uints per row (128 bf16)
    }
  }
}

// ---------------- CSR aggregation: one wave per node, bf16 gather, 8x MLP ----------------

__global__ __launch_bounds__(256) void aggregate(const uint* __restrict__ xw,
                                                 float* __restrict__ out,
                                                 const int* __restrict__ off,
                                                 const int* __restrict__ src_s,
                                                 const float* __restrict__ norm_s,
                                                 const float* __restrict__ dis,
                                                 const float* __restrict__ bias, int relu) {
  int wave = threadIdx.x >> 6;
  int lane = threadIdx.x & 63;
  int node = blockIdx.x * 4 + wave;
  if (node >= NN) return;
  float accx = 0.f, accy = 0.f;
  int s = off[node], e = off[node + 1];
  int idx = s;
  int astart = (s + 3) & ~3;
  if (astart > e) astart = e;
  for (; idx < astart; idx++) {
    int src = src_s[idx];
    float nm = norm_s[idx];
    uint u = xw[(size_t)src * 64 + lane];
    accx = fmaf(nm, __uint_as_float(u << 16), accx);
    accy = fmaf(nm, __uint_as_float(u & 0xffff0000u), accy);
  }
  for (; idx + 8 <= e; idx += 8) {
    int4 sa = *(const int4*)(src_s + idx);
    int4 sb = *(const int4*)(src_s + idx + 4);
    float4 na = *(const float4*)(norm_s + idx);
    float4 nb = *(const float4*)(norm_s + idx + 4);
    uint u0 = xw[(size_t)sa.x * 64 + lane];
    uint u1 = xw[(size_t)sa.y * 64 + lane];
    uint u2 = xw[(size_t)sa.z * 64 + lane];
    uint u3 = xw[(size_t)sa.w * 64 + lane];
    uint u4 = xw[(size_t)sb.x * 64 + lane];
    uint u5 = xw[(size_t)sb.y * 64 + lane];
    uint u6 = xw[(size_t)sb.z * 64 + lane];
    uint u7 = xw[(size_t)sb.w * 64 + lane];
    accx = fmaf(na.x, __uint_as_float(u0 << 16), accx);
    accy = fmaf(na.x, __uint_as_float(u0 & 0xffff0000u), accy);
    accx = fmaf(na.y, __uint_as_float(u1 << 16), accx);
    accy = fmaf(na.y, __uint_as_float(u1 & 0xffff0000u), accy);
    accx = fmaf(na.z, __uint_as_float(u2 << 16), accx);
    accy = fmaf(na.z, __uint_as_float(u2 & 0xffff0000u), accy);
    accx = fmaf(na.w, __uint_as_float(u3 << 16), accx);
    accy = fmaf(na.w, __uint_as_float(u3 & 0xffff0000u), accy);
    accx = fmaf(nb.x, __uint_as_float(u4 << 16), accx);
    accy = fmaf(nb.x, __uint_as_float(u4 & 0xffff0000u), accy);
    accx = fmaf(nb.y, __uint_as_float(u5 << 16), accx);
    accy = fmaf(nb.y, __uint_as_float(u5 & 0xffff0000u), accy);
    accx = fmaf(nb.z, __uint_as_float(u6 << 16), accx);
    accy = fmaf(nb.z, __uint_as_float(u6 & 0xffff0000u), accy);
    accx = fmaf(nb.w, __uint_as_float(u7 << 16), accx);
    accy = fmaf(nb.w, __uint_as_float(u7 & 0xffff0000u), accy);
  }
  for (; idx + 4 <= e; idx += 4) {
    int4 sr = *(const int4*)(src_s + idx);
    float4 nm = *(const float4*)(norm_s + idx);
    uint u0 = xw[(size_t)sr.x * 64 + lane];
    uint u1 = xw[(size_t)sr.y * 64 + lane];
    uint u2 = xw[(size_t)sr.z * 64 + lane];
    uint u3 = xw[(size_t)sr.w * 64 + lane];
    accx = fmaf(nm.x, __uint_as_float(u0 << 16), accx);
    accy = fmaf(nm.x, __uint_as_float(u0 & 0xffff0000u), accy);
    accx = fmaf(nm.y, __uint_as_float(u1 << 16), accx);
    accy = fmaf(nm.y, __uint_as_float(u1 & 0xffff0000u), accy);
    accx = fmaf(nm.z, __uint_as_float(u2 << 16), accx);
    accy = fmaf(nm.z, __uint_as_float(u2 & 0xffff0000u), accy);
    accx = fmaf(nm.w, __uint_as_float(u3 << 16), accx);
    accy = fmaf(nm.w, __uint_as_float(u3 & 0xffff0000u), accy);
  }
  for (; idx < e; idx++) {
    int src = src_s[idx];
    float nm = norm_s[idx];
    uint u = xw[(size_t)src * 64 + lane];
    accx = fmaf(nm, __uint_as_float(u << 16), accx);
    accy = fmaf(nm, __uint_as_float(u & 0xffff0000u), accy);
  }
  // self-loop
  float dd = dis[node];
  dd = dd * dd;
  {
    uint u = xw[(size_t)node * 64 + lane];
    accx = fmaf(dd, __uint_as_float(u << 16), accx);
    accy = fmaf(dd, __uint_as_float(u & 0xffff0000u), accy);
  }
  float2 b = ((const float2*)bias)[lane];
  accx += b.x;
  accy += b.y;
  if (relu) {
    accx = fmaxf(accx, 0.f);
    accy = fmaxf(accy, 0.f);
  }
  ((float2*)out)[(size_t)node * 64 + lane] = make_float2(accx, accy);
}

// ---------------- image GEMM via MFMA: xi = images @ W_img.T + b_img ----------------
// A (64x4096) preconverted to bf16; W loaded fp32, converted in-register.
// Grid (64 n-tiles of 64, 8 k-splits of 512). Block = 4 waves; wave w owns
// n-strip [bx*64 + w*16, +16), m = 0..63 (4 MFMA m-tiles), k-chunk 512.

__global__ void convA(const float* __restrict__ A, uint* __restrict__ Abf) {
  int idx = blockIdx.x * 256 + threadIdx.x;  // 64*4096/2 uints
  if (idx < 64 * IMG / 2) {
    float2 v = ((const float2*)A)[idx];
    Abf[idx] = pack2bf(v.x, v.y);
  }
}

__global__ __launch_bounds__(256) void img_mfma(const uint* __restrict__ Abf,
                                                const float* __restrict__ W,
                                                float* __restrict__ splitbuf) {
  int wv = threadIdx.x >> 6, lane = threadIdx.x & 63;
  int n = blockIdx.x * 64 + wv * 16 + (lane & 15);
  int kq = (lane >> 4) * 8;                  // quad's k offset within 32-step
  int k0 = blockIdx.y * 512 + kq;
  f32x4 acc[4] = {{0.f, 0.f, 0.f, 0.f}, {0.f, 0.f, 0.f, 0.f},
                  {0.f, 0.f, 0.f, 0.f}, {0.f, 0.f, 0.f, 0.f}};
  const float* wp = W + (size_t)n * IMG + k0;
  const uint* ap = Abf + (size_t)(lane & 15) * (IMG / 2) + k0 / 2;
  for (int ks = 0; ks < 512; ks += 32) {
    float4 w0 = *(const float4*)(wp + ks);
    float4 w1 = *(const float4*)(wp + ks + 4);
    union { uint4 u; bf16x8 v; } bu;
    bu.u.x = pack2bf(w0.x, w0.y);
    bu.u.y = pack2bf(w0.z, w0.w);
    bu.u.z = pack2bf(w1.x, w1.y);
    bu.u.w = pack2bf(w1.z, w1.w);
    #pragma unroll
    for (int mt = 0; mt < 4; mt++) {
      union { uint4 u; bf16x8 v; } au;
      au.u = *(const uint4*)(ap + (size_t)mt * 16 * (IMG / 2) + ks / 2);
      acc[mt] = __builtin_amdgcn_mfma_f32_16x16x32_bf16(au.v, bu.v, acc[mt], 0, 0, 0);
    }
  }
  // C/D layout: col(n)=lane&15, row(m)=(lane>>4)*4+i
  #pragma unroll
  for (int mt = 0; mt < 4; mt++)
    #pragma unroll
    for (int i = 0; i < 4; i++) {
      int m = mt * 16 + (lane >> 4) * 4 + i;
      splitbuf[((size_t)blockIdx.y * 64 + m) * IMG + n] = acc[mt][i];
    }
}

__global__ __launch_bounds__(256) void img_reduce(const float* __restrict__ splitbuf,
                                                  const float* __restrict__ bias,
                                                  float* __restrict__ xi) {
  int idx = blockIdx.x * 256 + threadIdx.x;  // 64*4096
  if (idx < 64 * IMG) {
    float acc = bias[idx & (IMG - 1)];
    #pragma unroll
    for (int s = 0; s < 8; s++) acc += splitbuf[(size_t)s * 64 * IMG + idx];
    xi[idx] = acc;
  }
}

// ---------------- small-M GEMM: out[64][N] += A[64][K] * W[N][K]^T, k-split ----------------

__global__ __launch_bounds__(256) void biasinit(float* __restrict__ out,
                                                const float* __restrict__ bias, int N) {
  int idx = blockIdx.x * 256 + threadIdx.x;
  if (idx < 64 * N) out[idx] = bias[idx % N];
}

__global__ __launch_bounds__(256) void gemm64(const float* __restrict__ A,
                                              const float* __restrict__ W,
                                              float* __restrict__ out, int N, int K,
                                              int kChunk) {
  __shared__ float xs[16][68];  // [k][m]
  __shared__ float ws[16][68];  // [k][n]
  int t = threadIdx.x;
  int n0 = blockIdx.x * 64;
  int k0 = blockIdx.y * kChunk;
  int kEnd = min(K, k0 + kChunk);
  int tn = t & 15;  // n = n0 + tn*4 + ni
  int tm = t >> 4;  // m = tm*4 + mi
  float acc[4][4] = {};
  for (int kt = k0; kt < kEnd; kt += 16) {
    int kc = (t & 3) * 4;
    int rr = t >> 2;  // 0..63
    float4 va = *(const float4*)(A + (size_t)rr * K + kt + kc);
    xs[kc + 0][rr] = va.x; xs[kc + 1][rr] = va.y; xs[kc + 2][rr] = va.z; xs[kc + 3][rr] = va.w;
    float4 vw = *(const float4*)(W + (size_t)(n0 + rr) * K + kt + kc);
    ws[kc + 0][rr] = vw.x; ws[kc + 1][rr] = vw.y; ws[kc + 2][rr] = vw.z; ws[kc + 3][rr] = vw.w;
    __syncthreads();
    #pragma unroll
    for (int k = 0; k < 16; k++) {
      float4 xv = *(const float4*)&xs[k][tm * 4];
      float4 wv = *(const float4*)&ws[k][tn * 4];
      float xm[4] = {xv.x, xv.y, xv.z, xv.w};
      float wn[4] = {wv.x, wv.y, wv.z, wv.w};
      #pragma unroll
      for (int mi = 0; mi < 4; mi++)
        #pragma unroll
        for (int ni = 0; ni < 4; ni++)
          acc[mi][ni] = fmaf(xm[mi], wn[ni], acc[mi][ni]);
    }
    __syncthreads();
  }
  #pragma unroll
  for (int mi = 0; mi < 4; mi++)
    #pragma unroll
    for (int ni = 0; ni < 4; ni++)
      atomicAdd(&out[(size_t)(tm * 4 + mi) * N + n0 + tn * 4 + ni], acc[mi][ni]);
}

// ---------------- pooling + heads ----------------

__global__ void graph_bounds(const int* __restrict__ batch, int* __restrict__ goff) {
  int g = threadIdx.x;
  if (g <= NG) {
    int lo = 0, hi = NN;
    while (lo < hi) {
      int mid = (lo + hi) >> 1;
      if (batch[mid] < g) lo = mid + 1; else hi = mid;
    }
    goff[g] = lo;
  }
}

__global__ __launch_bounds__(128) void pool_partial(const float* __restrict__ xg,
                                                    const int* __restrict__ goff,
                                                    float* __restrict__ pooled) {
  int g = blockIdx.x;
  int chunk = blockIdx.y;  // 0..7
  int t = threadIdx.x;
  int s = goff[g], e = goff[g + 1];
  float acc = 0.f;
  for (int i = s + chunk; i < e; i += 8) acc += xg[(size_t)i * D + t];
  atomicAdd(&pooled[g * D + t], acc);
}

__global__ __launch_bounds__(128) void pool_finish(float* __restrict__ pooled,
                                                   const int* __restrict__ goff) {
  int g = blockIdx.x;
  int t = threadIdx.x;
  int c = goff[g + 1] - goff[g];
  pooled[g * D + t] /= fmaxf((float)c, 1.0f);
}

__global__ __launch_bounds__(256) void build_xcat(const float* __restrict__ xi,
                                                  const float* __restrict__ pooled,
                                                  float* __restrict__ xcat) {
  int idx = blockIdx.x * 256 + threadIdx.x;  // 64 * 1056 float4s
  if (idx < 64 * 1056) {
    int r = idx / 1056;
    int c = idx % 1056;
    float4 v = (c < 1024) ? ((const float4*)xi)[r * 1024 + c]
                          : ((const float4*)pooled)[r * 32 + (c - 1024)];
    ((float4*)xcat)[idx] = v;
  }
}

__global__ __launch_bounds__(128) void normalize_rows(const float* __restrict__ oi_raw,
                                                      const float* __restrict__ oc_raw,
                                                      float* __restrict__ out) {
  int r = blockIdx.x;  // 0..127; 0..63 -> oi, 64..127 -> oc
  int t = threadIdx.x;
  const float* src = (r < 64) ? (oi_raw + r * D) : (oc_raw + (r - 64) * D);
  float v = src[t];
  __shared__ float red[128];
  red[t] = v * v;
  __syncthreads();
  for (int s = 64; s > 0; s >>= 1) {
    if (t < s) red[t] += red[t + s];
    __syncthreads();
  }
  out[r * D + t] = v / sqrtf(red[0]);
}

// ---------------- launch ----------------

extern "C" void kernel_launch(void* const* d_in, const int* in_sizes, int n_in,
                              void* d_out, int out_size, void* d_ws, size_t ws_size,
                              hipStream_t stream) {
  const float* images = (const float*)d_in[0];
  const int* node_types = (const int*)d_in[1];
  const int* erow = (const int*)d_in[2];
  const int* ecol = erow + NE;
  const float* eattr = (const float*)d_in[3];
  const int* batch = (const int*)d_in[4];
  const float* emb = (const float*)d_in[5];
  const float* W_img = (const float*)d_in[6];
  const float* b_img = (const float*)d_in[7];
  const float* W1 = (const float*)d_in[8];
  const float* b1 = (const float*)d_in[9];
  const float* W2 = (const float*)d_in[10];
  const float* b2 = (const float*)d_in[11];
  const float* W3 = (const float*)d_in[12];
  const float* b3 = (const float*)d_in[13];
  const float* Wi = (const float*)d_in[14];
  const float* bi = (const float*)d_in[15];
  const float* Wc = (const float*)d_in[16];
  const float* bc = (const float*)d_in[17];
  float* out = (float*)d_out;

  // workspace carve (512B aligned)
  char* w = (char*)d_ws;
  auto alloc = [&](size_t bytes) -> void* {
    void* p = (void*)w;
    w += (bytes + 511) & ~(size_t)511;
    return p;
  };
  int* cnt_i = (int*)alloc(NN * 4);
  float* pooled = (float*)alloc(64 * D * 4);
  size_t zero_bytes = (size_t)(w - (char*)d_ws);  // cnt + pooled need zeroing
  int* csr_off = (int*)alloc((NN + 1) * 4);
  int* goff = (int*)alloc((NG + 1) * 4);
  int* scan_incl = (int*)alloc(NN * 4);
  int* scan_part = (int*)alloc(SCAN_BLOCKS * 4);
  int* slot = (int*)alloc((size_t)NE * 4);
  int* src_s = (int*)alloc((size_t)NE * 4);
  float* ew_s = (float*)alloc((size_t)NE * 4);
  float* norm_s = (float*)alloc((size_t)NE * 4);
  float* dis = (float*)alloc(NN * 4);
  float* bufA = (float*)alloc((size_t)NN * D * 4);
  uint* bufB = (uint*)alloc((size_t)NN * D * 2);  // bf16 xw
  float* xi = (float*)alloc((size_t)64 * IMG * 4);
  float* xcat = (float*)alloc((size_t)64 * (IMG + D) * 4);
  float* oi_raw = (float*)alloc(64 * D * 4);
  float* oc_raw = (float*)alloc(64 * D * 4);
  uint* imgAbf = (uint*)alloc((size_t)64 * IMG * 2);           // bf16 images
  float* splitbuf = (float*)alloc((size_t)8 * 64 * IMG * 4);   // 8 k-splits

  hipMemsetAsync(d_ws, 0, zero_bytes, stream);

  // graph preprocessing (single per-edge atomic pass; fill is atomic-free)
  edge_slot<<<NE / 256, 256, 0, stream>>>(ecol, cnt_i, slot);
  scan_blocks<<<SCAN_BLOCKS, 256, 0, stream>>>(cnt_i, scan_incl, scan_part);
  scan_partials<<<1, 256, 0, stream>>>(scan_part, SCAN_BLOCKS);
  scan_apply<<<SCAN_BLOCKS, 256, 0, stream>>>(scan_incl, scan_part, csr_off);
  fill_scatter<<<NE / 256, 256, 0, stream>>>(erow, ecol, eattr, csr_off, slot, src_s, ew_s);
  deg_csr<<<(NN + 255) / 256, 256, 0, stream>>>(csr_off, ew_s, dis);
  norm_fill<<<(NN + 255) / 256, 256, 0, stream>>>(csr_off, src_s, ew_s, dis, norm_s);
  gather_emb<<<NN * 32 / 256, 256, 0, stream>>>(node_types, emb, bufA);

  // 3 GCN convs
  int nblk = (NN + 63) / 64;
  node_gemm<<<nblk, 256, 0, stream>>>(bufA, W1, bufB);
  aggregate<<<(NN + 3) / 4, 256, 0, stream>>>(bufB, bufA, csr_off, src_s, norm_s, dis, b1, 1);
  node_gemm<<<nblk, 256, 0, stream>>>(bufA, W2, bufB);
  aggregate<<<(NN + 3) / 4, 256, 0, stream>>>(bufB, bufA, csr_off, src_s, norm_s, dis, b2, 1);
  node_gemm<<<nblk, 256, 0, stream>>>(bufA, W3, bufB);
  aggregate<<<(NN + 3) / 4, 256, 0, stream>>>(bufB, bufA, csr_off, src_s, norm_s, dis, b3, 0);

  // pooling
  graph_bounds<<<1, 128, 0, stream>>>(batch, goff);
  {
    dim3 g(NG, 8);
    pool_partial<<<g, 128, 0, stream>>>(bufA, goff, pooled);
  }
  pool_finish<<<NG, 128, 0, stream>>>(pooled, goff);

  // image path: xi = images @ W_img.T + b_img  (bf16 MFMA, split-k)
  convA<<<(64 * IMG / 2 + 255) / 256, 256, 0, stream>>>(images, imgAbf);
  {
    dim3 g(IMG / 64, 8);
    img_mfma<<<g, 256, 0, stream>>>(imgAbf, W_img, splitbuf);
  }
  img_reduce<<<(64 * IMG + 255) / 256, 256, 0, stream>>>(splitbuf, b_img, xi);

  // oi = normalize(xi @ Wi.T + bi)
  biasinit<<<(64 * D + 255) / 256, 256, 0, stream>>>(oi_raw, bi, D);
  {
    dim3 g(D / 64, 32);
    gemm64<<<g, 256, 0, stream>>>(xi, Wi, oi_raw, D, IMG, 128);
  }
  // oc = normalize(concat(xi, pooled) @ Wc.T + bc)
  build_xcat<<<(64 * 1056 + 255) / 256, 256, 0, stream>>>(xi, pooled, xcat);
  biasinit<<<(64 * D + 255) / 256, 256, 0, stream>>>(oc_raw, bc, D);
  {
    dim3 g(D / 64, 24);
    gemm64<<<g, 256, 0, stream>>>(xcat, Wc, oc_raw, D, IMG + D, 176);
  }
  normalize_rows<<<128, 128, 0, stream>>>(oi_raw, oc_raw, out);
}

// Round 6
// 512.303 us; speedup vs baseline: 1.6854x; 1.0793x over previous
//
#include <hip/hip_runtime.h>
#include <math.h>

#define NN 50000
#define NE 800000
#define NG 64
#define D 128
#define IMG 4096
#define NT 30
#define SCAN_BLOCKS ((NN + 255) / 256)

typedef unsigned int uint;
typedef __attribute__((ext_vector_type(8))) __bf16 bf16x8;
typedef __attribute__((ext_vector_type(4))) float f32x4;

// bf16 helpers (bit-level, RNE pack / shift unpack)
__device__ __forceinline__ uint bf16rne(float f) {
  uint h = __float_as_uint(f);
  return (h + 0x7fffu + ((h >> 16) & 1u)) >> 16;
}
__device__ __forceinline__ uint pack2bf(float a, float b) {
  return bf16rne(a) | (bf16rne(b) << 16);
}

// ---------------- graph preprocessing ----------------

// pass 1: count in-edges per node; atomic return value IS the CSR slot
__global__ void edge_slot(const int* __restrict__ col, int* __restrict__ cnt,
                          int* __restrict__ slot) {
  int e = blockIdx.x * 256 + threadIdx.x;
  if (e < NE) {
    int c = col[e];
    slot[e] = atomicAdd(&cnt[c], 1);
  }
}

// ---- 3-level parallel exclusive scan of cnt[NN] -> off[NN+1] ----

__global__ __launch_bounds__(256) void scan_blocks(const int* __restrict__ cnt,
                                                   int* __restrict__ incl,
                                                   int* __restrict__ partial) {
  __shared__ int sd[256];
  int t = threadIdx.x;
  int i = blockIdx.x * 256 + t;
  int v = (i < NN) ? cnt[i] : 0;
  sd[t] = v;
  __syncthreads();
  #pragma unroll
  for (int s = 1; s < 256; s <<= 1) {
    int add = (t >= s) ? sd[t - s] : 0;
    __syncthreads();
    sd[t] += add;
    __syncthreads();
  }
  if (i < NN) incl[i] = sd[t];
  if (t == 255) partial[blockIdx.x] = sd[255];
}

__global__ __launch_bounds__(256) void scan_partials(int* __restrict__ partial, int nb) {
  __shared__ int sd[256];
  int t = threadIdx.x;
  int v = (t < nb) ? partial[t] : 0;
  sd[t] = v;
  __syncthreads();
  #pragma unroll
  for (int s = 1; s < 256; s <<= 1) {
    int add = (t >= s) ? sd[t - s] : 0;
    __syncthreads();
    sd[t] += add;
    __syncthreads();
  }
  if (t < nb) partial[t] = (t == 0) ? 0 : sd[t - 1];
}

__global__ __launch_bounds__(256) void scan_apply(const int* __restrict__ incl,
                                                  const int* __restrict__ partial,
                                                  int* __restrict__ off) {
  int i = blockIdx.x * 256 + threadIdx.x;
  if (i < NN) off[i + 1] = incl[i] + partial[blockIdx.x];
  if (i == 0) off[0] = 0;
}

// pass 2: atomic-free scatter into CSR
__global__ void fill_scatter(const int* __restrict__ row, const int* __restrict__ col,
                             const float* __restrict__ ew, const int* __restrict__ off,
                             const int* __restrict__ slot, int* __restrict__ src_s,
                             float* __restrict__ ew_s) {
  int e = blockIdx.x * 256 + threadIdx.x;
  if (e < NE) {
    int idx = off[col[e]] + slot[e];
    src_s[idx] = row[e];
    ew_s[idx] = ew[e];
  }
}

// segmented sum of ew per node -> dis = rsqrt(deg+1)
__global__ void deg_csr(const int* __restrict__ off, const float* __restrict__ ew_s,
                        float* __restrict__ dis) {
  int i = blockIdx.x * 256 + threadIdx.x;
  if (i < NN) {
    int s = off[i], e = off[i + 1];
    float acc = 0.f;
    for (int j = s; j < e; j++) acc += ew_s[j];
    dis[i] = 1.0f / sqrtf(acc + 1.0f);
  }
}

// norm_s[idx] = dis[src] * ew * dis[c]; also record src node type for layer-1
__global__ void norm_fill(const int* __restrict__ off, const int* __restrict__ src_s,
                          const float* __restrict__ ew_s, const float* __restrict__ dis,
                          const int* __restrict__ types, float* __restrict__ norm_s,
                          int* __restrict__ styp_s) {
  int i = blockIdx.x * 256 + threadIdx.x;
  if (i < NN) {
    int s = off[i], e = off[i + 1];
    float dc = dis[i];
    for (int j = s; j < e; j++) {
      int sv = src_s[j];
      norm_s[j] = dis[sv] * ew_s[j] * dc;
      styp_s[j] = types[sv];
    }
  }
}

// embW[t][n] = sum_k emb[t][k] * W1[n][k]   (30 x 128)
__global__ void embw_k(const float* __restrict__ emb, const float* __restrict__ W,
                       float* __restrict__ embW) {
  int tid = blockIdx.x * 256 + threadIdx.x;
  if (tid < NT * D) {
    int t = tid >> 7, n = tid & 127;
    const float* e = emb + (size_t)t * D;
    const float* w = W + (size_t)n * D;
    float acc = 0.f;
    for (int k = 0; k < D; k += 4) {
      float4 ev = *(const float4*)(e + k);
      float4 wv = *(const float4*)(w + k);
      acc += ev.x * wv.x + ev.y * wv.y + ev.z * wv.z + ev.w * wv.w;
    }
    embW[tid] = acc;
  }
}

// ---------------- layer 1 fused: out = relu(C @ embW1 + b1) ----------------
// C[i,t] = sum_{in-edges, srctype t} norm + dis_i^2 * [type_i == t].
// 16 nodes/block (4 per wave). Edge loop reads 8 B/edge instead of a 256 B row.

__global__ __launch_bounds__(256) void lay1_fused(const int* __restrict__ off,
                                                  const int* __restrict__ styp_s,
                                                  const float* __restrict__ norm_s,
                                                  const float* __restrict__ dis,
                                                  const int* __restrict__ types,
                                                  const float* __restrict__ embW,
                                                  const float* __restrict__ b1,
                                                  float* __restrict__ out) {
  __shared__ float sE[NT * D];   // 15360 B
  __shared__ float sC[16][32];   // 2048 B (pad 30->32)
  __shared__ float sB[D];
  int t = threadIdx.x;
  for (int i = t; i < NT * D; i += 256) sE[i] = embW[i];
  if (t < D) sB[t] = b1[t];
  for (int i = t; i < 16 * 32; i += 256) ((float*)sC)[i] = 0.f;
  __syncthreads();
  int wave = t >> 6, lane = t & 63;
  int nodebase = blockIdx.x * 16;
  #pragma unroll
  for (int r = 0; r < 4; r++) {
    int li = wave * 4 + r;
    int node = nodebase + li;
    if (node < NN) {
      int s = off[node], e = off[node + 1];
      for (int idx = s + lane; idx < e; idx += 64)
        atomicAdd(&sC[li][styp_s[idx]], norm_s[idx]);
      if (lane == 0) {
        float dd = dis[node];
        atomicAdd(&sC[li][types[node]], dd * dd);
      }
    }
  }
  __syncthreads();
  #pragma unroll
  for (int r = 0; r < 4; r++) {
    int li = wave * 4 + r;
    int node = nodebase + li;
    if (node < NN) {
      float2 acc = *(const float2*)&sB[lane * 2];
      #pragma unroll
      for (int tt = 0; tt < NT; tt++) {
        float c = sC[li][tt];
        float2 ev = *(const float2*)&sE[tt * D + lane * 2];
        acc.x = fmaf(c, ev.x, acc.x);
        acc.y = fmaf(c, ev.y, acc.y);
      }
      acc.x = fmaxf(acc.x, 0.f);
      acc.y = fmaxf(acc.y, 0.f);
      ((float2*)out)[(size_t)node * 64 + lane] = acc;
    }
  }
}

// ---------------- node GEMM: out[i][n] = sum_k x[i][k] * W[n][k], K=D=128 ----------------
// Output packed bf16 (RNE) for the aggregation gather.

__global__ __launch_bounds__(256) void node_gemm(const float* __restrict__ x,
                                                 const float* __restrict__ W,
                                                 uint* __restrict__ outbf) {
  __shared__ float xs[16][68];   // [k][m]
  __shared__ float ws[16][132];  // [k][n]
  int t = threadIdx.x;
  int m0 = blockIdx.x * 64;
  int tm = t >> 4;  // 0..15 -> m = m0 + tm*4 + mi
  int tn = t & 15;  // 0..15 -> n = tn*8 + nj
  float acc[4][8] = {};
  for (int kt = 0; kt < D; kt += 16) {
    {  // stage x tile [64 m x 16 k] transposed
      int mm = m0 + (t >> 2);
      int kc = (t & 3) * 4;
      float4 v = make_float4(0.f, 0.f, 0.f, 0.f);
      if (mm < NN) v = *(const float4*)(x + (size_t)mm * D + kt + kc);
      int ml = t >> 2;
      xs[kc + 0][ml] = v.x; xs[kc + 1][ml] = v.y; xs[kc + 2][ml] = v.z; xs[kc + 3][ml] = v.w;
    }
    {  // stage W tile [128 n x 16 k] transposed
      int kc = (t & 3) * 4;
      #pragma unroll
      for (int r = 0; r < 2; r++) {
        int nn = (t >> 2) + r * 64;
        float4 v = *(const float4*)(W + (size_t)nn * D + kt + kc);
        ws[kc + 0][nn] = v.x; ws[kc + 1][nn] = v.y; ws[kc + 2][nn] = v.z; ws[kc + 3][nn] = v.w;
      }
    }
    __syncthreads();
    #pragma unroll
    for (int k = 0; k < 16; k++) {
      float4 xv = *(const float4*)&xs[k][tm * 4];
      float4 wa = *(const float4*)&ws[k][tn * 8];
      float4 wb = *(const float4*)&ws[k][tn * 8 + 4];
      float xm[4] = {xv.x, xv.y, xv.z, xv.w};
      float wn[8] = {wa.x, wa.y, wa.z, wa.w, wb.x, wb.y, wb.z, wb.w};
      #pragma unroll
      for (int mi = 0; mi < 4; mi++)
        #pragma unroll
        for (int nj = 0; nj < 8; nj++)
          acc[mi][nj] = fmaf(xm[mi], wn[nj], acc[mi][nj]);
    }
    __syncthreads();
  }
  #pragma unroll
  for (int mi = 0; mi < 4; mi++) {
    int mm = m0 + tm * 4 + mi;
    if (mm < NN) {
      uint4 o;
      o.x = pack2bf(acc[mi][0], acc[mi][1]);
      o.y = pack2bf(acc[mi][2], acc[mi][3]);
      o.z = pack2bf(acc[mi][4], acc[mi][5]);
      o.w = pack2bf(acc[mi][6], acc[mi][7]);
      *(uint4*)(outbf + (size_t)mm * 64 + tn * 4) = o;  // 64 uints per row (128 bf16)
    }
  }
}

// ---------------- CSR aggregation: one wave per node, bf16 gather, 8x MLP ----------------

__global__ __launch_bounds__(256) void aggregate(const uint* __restrict__ xw,
                                                 float* __restrict__ out,
                                                 const int* __restrict__ off,
                                                 const int* __restrict__ src_s,
                                                 const float* __restrict__ norm_s,
                                                 const float* __restrict__ dis,
                                                 const float* __restrict__ bias, int relu) {
  int wave = threadIdx.x >> 6;
  int lane = threadIdx.x & 63;
  int node = blockIdx.x * 4 + wave;
  if (node >= NN) return;
  float accx = 0.f, accy = 0.f;
  int s = off[node], e = off[node + 1];
  int idx = s;
  int astart = (s + 3) & ~3;
  if (astart > e) astart = e;
  for (; idx < astart; idx++) {
    int src = src_s[idx];
    float nm = norm_s[idx];
    uint u = xw[(size_t)src * 64 + lane];
    accx = fmaf(nm, __uint_as_float(u << 16), accx);
    accy = fmaf(nm, __uint_as_float(u & 0xffff0000u), accy);
  }
  for (; idx + 8 <= e; idx += 8) {
    int4 sa = *(const int4*)(src_s + idx);
    int4 sb = *(const int4*)(src_s + idx + 4);
    float4 na = *(const float4*)(norm_s + idx);
    float4 nb = *(const float4*)(norm_s + idx + 4);
    uint u0 = xw[(size_t)sa.x * 64 + lane];
    uint u1 = xw[(size_t)sa.y * 64 + lane];
    uint u2 = xw[(size_t)sa.z * 64 + lane];
    uint u3 = xw[(size_t)sa.w * 64 + lane];
    uint u4 = xw[(size_t)sb.x * 64 + lane];
    uint u5 = xw[(size_t)sb.y * 64 + lane];
    uint u6 = xw[(size_t)sb.z * 64 + lane];
    uint u7 = xw[(size_t)sb.w * 64 + lane];
    accx = fmaf(na.x, __uint_as_float(u0 << 16), accx);
    accy = fmaf(na.x, __uint_as_float(u0 & 0xffff0000u), accy);
    accx = fmaf(na.y, __uint_as_float(u1 << 16), accx);
    accy = fmaf(na.y, __uint_as_float(u1 & 0xffff0000u), accy);
    accx = fmaf(na.z, __uint_as_float(u2 << 16), accx);
    accy = fmaf(na.z, __uint_as_float(u2 & 0xffff0000u), accy);
    accx = fmaf(na.w, __uint_as_float(u3 << 16), accx);
    accy = fmaf(na.w, __uint_as_float(u3 & 0xffff0000u), accy);
    accx = fmaf(nb.x, __uint_as_float(u4 << 16), accx);
    accy = fmaf(nb.x, __uint_as_float(u4 & 0xffff0000u), accy);
    accx = fmaf(nb.y, __uint_as_float(u5 << 16), accx);
    accy = fmaf(nb.y, __uint_as_float(u5 & 0xffff0000u), accy);
    accx = fmaf(nb.z, __uint_as_float(u6 << 16), accx);
    accy = fmaf(nb.z, __uint_as_float(u6 & 0xffff0000u), accy);
    accx = fmaf(nb.w, __uint_as_float(u7 << 16), accx);
    accy = fmaf(nb.w, __uint_as_float(u7 & 0xffff0000u), accy);
  }
  for (; idx + 4 <= e; idx += 4) {
    int4 sr = *(const int4*)(src_s + idx);
    float4 nm = *(const float4*)(norm_s + idx);
    uint u0 = xw[(size_t)sr.x * 64 + lane];
    uint u1 = xw[(size_t)sr.y * 64 + lane];
    uint u2 = xw[(size_t)sr.z * 64 + lane];
    uint u3 = xw[(size_t)sr.w * 64 + lane];
    accx = fmaf(nm.x, __uint_as_float(u0 << 16), accx);
    accy = fmaf(nm.x, __uint_as_float(u0 & 0xffff0000u), accy);
    accx = fmaf(nm.y, __uint_as_float(u1 << 16), accx);
    accy = fmaf(nm.y, __uint_as_float(u1 & 0xffff0000u), accy);
    accx = fmaf(nm.z, __uint_as_float(u2 << 16), accx);
    accy = fmaf(nm.z, __uint_as_float(u2 & 0xffff0000u), accy);
    accx = fmaf(nm.w, __uint_as_float(u3 << 16), accx);
    accy = fmaf(nm.w, __uint_as_float(u3 & 0xffff0000u), accy);
  }
  for (; idx < e; idx++) {
    int src = src_s[idx];
    float nm = norm_s[idx];
    uint u = xw[(size_t)src * 64 + lane];
    accx = fmaf(nm, __uint_as_float(u << 16), accx);
    accy = fmaf(nm, __uint_as_float(u & 0xffff0000u), accy);
  }
  // self-loop
  float dd = dis[node];
  dd = dd * dd;
  {
    uint u = xw[(size_t)node * 64 + lane];
    accx = fmaf(dd, __uint_as_float(u << 16), accx);
    accy = fmaf(dd, __uint_as_float(u & 0xffff0000u), accy);
  }
  float2 b = ((const float2*)bias)[lane];
  accx += b.x;
  accy += b.y;
  if (relu) {
    accx = fmaxf(accx, 0.f);
    accy = fmaxf(accy, 0.f);
  }
  ((float2*)out)[(size_t)node * 64 + lane] = make_float2(accx, accy);
}

// ---------------- image GEMM via MFMA: xi = images @ W_img.T + b_img ----------------

__global__ void convA(const float* __restrict__ A, uint* __restrict__ Abf) {
  int idx = blockIdx.x * 256 + threadIdx.x;  // 64*4096/2 uints
  if (idx < 64 * IMG / 2) {
    float2 v = ((const float2*)A)[idx];
    Abf[idx] = pack2bf(v.x, v.y);
  }
}

__global__ __launch_bounds__(256) void img_mfma(const uint* __restrict__ Abf,
                                                const float* __restrict__ W,
                                                float* __restrict__ splitbuf) {
  int wv = threadIdx.x >> 6, lane = threadIdx.x & 63;
  int n = blockIdx.x * 64 + wv * 16 + (lane & 15);
  int kq = (lane >> 4) * 8;                  // quad's k offset within 32-step
  int k0 = blockIdx.y * 512 + kq;
  f32x4 acc[4] = {{0.f, 0.f, 0.f, 0.f}, {0.f, 0.f, 0.f, 0.f},
                  {0.f, 0.f, 0.f, 0.f}, {0.f, 0.f, 0.f, 0.f}};
  const float* wp = W + (size_t)n * IMG + k0;
  const uint* ap = Abf + (size_t)(lane & 15) * (IMG / 2) + k0 / 2;
  for (int ks = 0; ks < 512; ks += 32) {
    float4 w0 = *(const float4*)(wp + ks);
    float4 w1 = *(const float4*)(wp + ks + 4);
    union { uint4 u; bf16x8 v; } bu;
    bu.u.x = pack2bf(w0.x, w0.y);
    bu.u.y = pack2bf(w0.z, w0.w);
    bu.u.z = pack2bf(w1.x, w1.y);
    bu.u.w = pack2bf(w1.z, w1.w);
    #pragma unroll
    for (int mt = 0; mt < 4; mt++) {
      union { uint4 u; bf16x8 v; } au;
      au.u = *(const uint4*)(ap + (size_t)mt * 16 * (IMG / 2) + ks / 2);
      acc[mt] = __builtin_amdgcn_mfma_f32_16x16x32_bf16(au.v, bu.v, acc[mt], 0, 0, 0);
    }
  }
  // C/D layout: col(n)=lane&15, row(m)=(lane>>4)*4+i
  #pragma unroll
  for (int mt = 0; mt < 4; mt++)
    #pragma unroll
    for (int i = 0; i < 4; i++) {
      int m = mt * 16 + (lane >> 4) * 4 + i;
      splitbuf[((size_t)blockIdx.y * 64 + m) * IMG + n] = acc[mt][i];
    }
}

__global__ __launch_bounds__(256) void img_reduce(const float* __restrict__ splitbuf,
                                                  const float* __restrict__ bias,
                                                  float* __restrict__ xi) {
  int idx = blockIdx.x * 256 + threadIdx.x;  // 64*4096
  if (idx < 64 * IMG) {
    float acc = bias[idx & (IMG - 1)];
    #pragma unroll
    for (int s = 0; s < 8; s++) acc += splitbuf[(size_t)s * 64 * IMG + idx];
    xi[idx] = acc;
  }
}

// ---------------- small-M GEMM: out[64][N] += A[64][K] * W[N][K]^T, k-split ----------------

__global__ __launch_bounds__(256) void biasinit(float* __restrict__ out,
                                                const float* __restrict__ bias, int N) {
  int idx = blockIdx.x * 256 + threadIdx.x;
  if (idx < 64 * N) out[idx] = bias[idx % N];
}

__global__ __launch_bounds__(256) void gemm64(const float* __restrict__ A,
                                              const float* __restrict__ W,
                                              float* __restrict__ out, int N, int K,
                                              int kChunk) {
  __shared__ float xs[16][68];  // [k][m]
  __shared__ float ws[16][68];  // [k][n]
  int t = threadIdx.x;
  int n0 = blockIdx.x * 64;
  int k0 = blockIdx.y * kChunk;
  int kEnd = min(K, k0 + kChunk);
  int tn = t & 15;  // n = n0 + tn*4 + ni
  int tm = t >> 4;  // m = tm*4 + mi
  float acc[4][4] = {};
  for (int kt = k0; kt < kEnd; kt += 16) {
    int kc = (t & 3) * 4;
    int rr = t >> 2;  // 0..63
    float4 va = *(const float4*)(A + (size_t)rr * K + kt + kc);
    xs[kc + 0][rr] = va.x; xs[kc + 1][rr] = va.y; xs[kc + 2][rr] = va.z; xs[kc + 3][rr] = va.w;
    float4 vw = *(const float4*)(W + (size_t)(n0 + rr) * K + kt + kc);
    ws[kc + 0][rr] = vw.x; ws[kc + 1][rr] = vw.y; ws[kc + 2][rr] = vw.z; ws[kc + 3][rr] = vw.w;
    __syncthreads();
    #pragma unroll
    for (int k = 0; k < 16; k++) {
      float4 xv = *(const float4*)&xs[k][tm * 4];
      float4 wv = *(const float4*)&ws[k][tn * 4];
      float xm[4] = {xv.x, xv.y, xv.z, xv.w};
      float wn[4] = {wv.x, wv.y, wv.z, wv.w};
      #pragma unroll
      for (int mi = 0; mi < 4; mi++)
        #pragma unroll
        for (int ni = 0; ni < 4; ni++)
          acc[mi][ni] = fmaf(xm[mi], wn[ni], acc[mi][ni]);
    }
    __syncthreads();
  }
  #pragma unroll
  for (int mi = 0; mi < 4; mi++)
    #pragma unroll
    for (int ni = 0; ni < 4; ni++)
      atomicAdd(&out[(size_t)(tm * 4 + mi) * N + n0 + tn * 4 + ni], acc[mi][ni]);
}

// ---------------- pooling + heads ----------------

__global__ void graph_bounds(const int* __restrict__ batch, int* __restrict__ goff) {
  int g = threadIdx.x;
  if (g <= NG) {
    int lo = 0, hi = NN;
    while (lo < hi) {
      int mid = (lo + hi) >> 1;
      if (batch[mid] < g) lo = mid + 1; else hi = mid;
    }
    goff[g] = lo;
  }
}

__global__ __launch_bounds__(128) void pool_partial(const float* __restrict__ xg,
                                                    const int* __restrict__ goff,
                                                    float* __restrict__ pooled) {
  int g = blockIdx.x;
  int chunk = blockIdx.y;  // 0..7
  int t = threadIdx.x;
  int s = goff[g], e = goff[g + 1];
  float acc = 0.f;
  for (int i = s + chunk; i < e; i += 8) acc += xg[(size_t)i * D + t];
  atomicAdd(&pooled[g * D + t], acc);
}

__global__ __launch_bounds__(128) void pool_finish(float* __restrict__ pooled,
                                                   const int* __restrict__ goff) {
  int g = blockIdx.x;
  int t = threadIdx.x;
  int c = goff[g + 1] - goff[g];
  pooled[g * D + t] /= fmaxf((float)c, 1.0f);
}

__global__ __launch_bounds__(256) void build_xcat(const float* __restrict__ xi,
                                                  const float* __restrict__ pooled,
                                                  float* __restrict__ xcat) {
  int idx = blockIdx.x * 256 + threadIdx.x;  // 64 * 1056 float4s
  if (idx < 64 * 1056) {
    int r = idx / 1056;
    int c = idx % 1056;
    float4 v = (c < 1024) ? ((const float4*)xi)[r * 1024 + c]
                          : ((const float4*)pooled)[r * 32 + (c - 1024)];
    ((float4*)xcat)[idx] = v;
  }
}

__global__ __launch_bounds__(128) void normalize_rows(const float* __restrict__ oi_raw,
                                                      const float* __restrict__ oc_raw,
                                                      float* __restrict__ out) {
  int r = blockIdx.x;  // 0..127; 0..63 -> oi, 64..127 -> oc
  int t = threadIdx.x;
  const float* src = (r < 64) ? (oi_raw + r * D) : (oc_raw + (r - 64) * D);
  float v = src[t];
  __shared__ float red[128];
  red[t] = v * v;
  __syncthreads();
  for (int s = 64; s > 0; s >>= 1) {
    if (t < s) red[t] += red[t + s];
    __syncthreads();
  }
  out[r * D + t] = v / sqrtf(red[0]);
}

// ---------------- launch ----------------

extern "C" void kernel_launch(void* const* d_in, const int* in_sizes, int n_in,
                              void* d_out, int out_size, void* d_ws, size_t ws_size,
                              hipStream_t stream) {
  const float* images = (const float*)d_in[0];
  const int* node_types = (const int*)d_in[1];
  const int* erow = (const int*)d_in[2];
  const int* ecol = erow + NE;
  const float* eattr = (const float*)d_in[3];
  const int* batch = (const int*)d_in[4];
  const float* emb = (const float*)d_in[5];
  const float* W_img = (const float*)d_in[6];
  const float* b_img = (const float*)d_in[7];
  const float* W1 = (const float*)d_in[8];
  const float* b1 = (const float*)d_in[9];
  const float* W2 = (const float*)d_in[10];
  const float* b2 = (const float*)d_in[11];
  const float* W3 = (const float*)d_in[12];
  const float* b3 = (const float*)d_in[13];
  const float* Wi = (const float*)d_in[14];
  const float* bi = (const float*)d_in[15];
  const float* Wc = (const float*)d_in[16];
  const float* bc = (const float*)d_in[17];
  float* out = (float*)d_out;

  // workspace carve (512B aligned)
  char* w = (char*)d_ws;
  auto alloc = [&](size_t bytes) -> void* {
    void* p = (void*)w;
    w += (bytes + 511) & ~(size_t)511;
    return p;
  };
  int* cnt_i = (int*)alloc(NN * 4);
  float* pooled = (float*)alloc(64 * D * 4);
  size_t zero_bytes = (size_t)(w - (char*)d_ws);  // cnt + pooled need zeroing
  int* csr_off = (int*)alloc((NN + 1) * 4);
  int* goff = (int*)alloc((NG + 1) * 4);
  int* scan_incl = (int*)alloc(NN * 4);
  int* scan_part = (int*)alloc(SCAN_BLOCKS * 4);
  int* slot = (int*)alloc((size_t)NE * 4);
  int* src_s = (int*)alloc((size_t)NE * 4);
  float* ew_s = (float*)alloc((size_t)NE * 4);
  float* norm_s = (float*)alloc((size_t)NE * 4);
  int* styp_s = (int*)alloc((size_t)NE * 4);
  float* dis = (float*)alloc(NN * 4);
  float* embW1 = (float*)alloc(NT * D * 4);
  float* bufA = (float*)alloc((size_t)NN * D * 4);
  uint* bufB = (uint*)alloc((size_t)NN * D * 2);  // bf16 xw
  float* xi = (float*)alloc((size_t)64 * IMG * 4);
  float* xcat = (float*)alloc((size_t)64 * (IMG + D) * 4);
  float* oi_raw = (float*)alloc(64 * D * 4);
  float* oc_raw = (float*)alloc(64 * D * 4);
  uint* imgAbf = (uint*)alloc((size_t)64 * IMG * 2);           // bf16 images
  float* splitbuf = (float*)alloc((size_t)8 * 64 * IMG * 4);   // 8 k-splits

  hipMemsetAsync(d_ws, 0, zero_bytes, stream);

  // graph preprocessing (single per-edge atomic pass; fill is atomic-free)
  edge_slot<<<NE / 256, 256, 0, stream>>>(ecol, cnt_i, slot);
  scan_blocks<<<SCAN_BLOCKS, 256, 0, stream>>>(cnt_i, scan_incl, scan_part);
  scan_partials<<<1, 256, 0, stream>>>(scan_part, SCAN_BLOCKS);
  scan_apply<<<SCAN_BLOCKS, 256, 0, stream>>>(scan_incl, scan_part, csr_off);
  fill_scatter<<<NE / 256, 256, 0, stream>>>(erow, ecol, eattr, csr_off, slot, src_s, ew_s);
  deg_csr<<<(NN + 255) / 256, 256, 0, stream>>>(csr_off, ew_s, dis);
  norm_fill<<<(NN + 255) / 256, 256, 0, stream>>>(csr_off, src_s, ew_s, dis, node_types,
                                                  norm_s, styp_s);

  // layer 1 collapsed: out1 = relu(C @ (emb @ W1^T) + b1)
  embw_k<<<(NT * D + 255) / 256, 256, 0, stream>>>(emb, W1, embW1);
  lay1_fused<<<(NN + 15) / 16, 256, 0, stream>>>(csr_off, styp_s, norm_s, dis, node_types,
                                                 embW1, b1, bufA);

  // layers 2 & 3
  int nblk = (NN + 63) / 64;
  node_gemm<<<nblk, 256, 0, stream>>>(bufA, W2, bufB);
  aggregate<<<(NN + 3) / 4, 256, 0, stream>>>(bufB, bufA, csr_off, src_s, norm_s, dis, b2, 1);
  node_gemm<<<nblk, 256, 0, stream>>>(bufA, W3, bufB);
  aggregate<<<(NN + 3) / 4, 256, 0, stream>>>(bufB, bufA, csr_off, src_s, norm_s, dis, b3, 0);

  // pooling
  graph_bounds<<<1, 128, 0, stream>>>(batch, goff);
  {
    dim3 g(NG, 8);
    pool_partial<<<g, 128, 0, stream>>>(bufA, goff, pooled);
  }
  pool_finish<<<NG, 128, 0, stream>>>(pooled, goff);

  // image path: xi = images @ W_img.T + b_img  (bf16 MFMA, split-k)
  convA<<<(64 * IMG / 2 + 255) / 256, 256, 0, stream>>>(images, imgAbf);
  {
    dim3 g(IMG / 64, 8);
    img_mfma<<<g, 256, 0, stream>>>(imgAbf, W_img, splitbuf);
  }
  img_reduce<<<(64 * IMG + 255) / 256, 256, 0, stream>>>(splitbuf, b_img, xi);

  // oi = normalize(xi @ Wi.T + bi)
  biasinit<<<(64 * D + 255) / 256, 256, 0, stream>>>(oi_raw, bi, D);
  {
    dim3 g(D / 64, 32);
    gemm64<<<g, 256, 0, stream>>>(xi, Wi, oi_raw, D, IMG, 128);
  }
  // oc = normalize(concat(xi, pooled) @ Wc.T + bc)
  build_xcat<<<(64 * 1056 + 255) / 256, 256, 0, stream>>>(xi, pooled, xcat);
  biasinit<<<(64 * D + 255) / 256, 256, 0, stream>>>(oc_raw, bc, D);
  {
    dim3 g(D / 64, 24);
    gemm64<<<g, 256, 0, stream>>>(xcat, Wc, oc_raw, D, IMG + D, 176);
  }
  normalize_rows<<<128, 128, 0, stream>>>(oi_raw, oc_raw, out);
}